// Round 6
// baseline (268.120 us; speedup 1.0000x reference)
//
#include <hip/hip_runtime.h>
#include <hip/hip_bf16.h>
#include <math.h>

typedef __attribute__((ext_vector_type(8))) short bf16x8;
typedef __attribute__((ext_vector_type(4))) float f32x4;

static __device__ inline ushort f2bf(float f) {
    union { float f; unsigned u; } v; v.f = f;
    unsigned r = (v.u + 0x7fff + ((v.u >> 16) & 1)) >> 16;   // RNE
    return (ushort)r;
}

#define GLD_LDS(g, l) \
    __builtin_amdgcn_global_load_lds( \
        (const __attribute__((address_space(1))) void*)(g), \
        (__attribute__((address_space(3))) void*)(l), 16, 0, 0)

#define MFMA_BF16(a, b, c) __builtin_amdgcn_mfma_f32_16x16x32_bf16((a), (b), (c), 0, 0, 0)

// ---------------------------------------------------------------------------
// x fp32 -> bf16
// ---------------------------------------------------------------------------
__global__ __launch_bounds__(256) void convert_x(
    const float* __restrict__ x, ushort* __restrict__ xb)
{
    const size_t i = ((size_t)blockIdx.x * 256 + threadIdx.x) * 8;
    float4 a = *(const float4*)(x + i);
    float4 b = *(const float4*)(x + i + 4);
    bf16x8 t;
    t[0] = (short)f2bf(a.x); t[1] = (short)f2bf(a.y);
    t[2] = (short)f2bf(a.z); t[3] = (short)f2bf(a.w);
    t[4] = (short)f2bf(b.x); t[5] = (short)f2bf(b.y);
    t[6] = (short)f2bf(b.z); t[7] = (short)f2bf(b.w);
    *(bf16x8*)(xb + i) = t;
}

// ---------------------------------------------------------------------------
// Weights fp32 [K][N] -> Wt bf16 [4096][1024] transposed
// ---------------------------------------------------------------------------
__global__ __launch_bounds__(256) void prep_w(
    const float* __restrict__ Wq, const float* __restrict__ Wkv,
    const float* __restrict__ Wo, ushort* __restrict__ Wt)
{
    const int w = threadIdx.x >> 6;
    const int lane = threadIdx.x & 63;
    const int tile = blockIdx.x * 4 + w;
    const int r0 = (tile >> 4) << 6;
    const int k0 = (tile & 15) << 6;

    const float* src; int ld, c0;
    if (r0 < 1024)      { src = Wq;  ld = 1024; c0 = r0; }
    else if (r0 < 3072) { src = Wkv; ld = 2048; c0 = r0 - 1024; }
    else                { src = Wo;  ld = 1024; c0 = r0 - 3072; }

    ushort v[64];
    #pragma unroll
    for (int k = 0; k < 64; ++k)
        v[k] = f2bf(src[(size_t)(k0 + k) * ld + c0 + lane]);

    ushort* dst = Wt + (size_t)(r0 + lane) * 1024 + k0;
    #pragma unroll
    for (int k = 0; k < 64; k += 8) {
        bf16x8 t;
        #pragma unroll
        for (int j = 0; j < 8; ++j) t[j] = (short)v[k + j];
        *(bf16x8*)(dst + k) = t;
    }
}

// ---------------------------------------------------------------------------
// gemm_qkv: 256x256 tile, BK=64, 512 thr / 8 waves (2M x 4N), per-wave 128x64.
// SINGLE-barrier-per-K-tile pipelined loop: all 24 ds_read_b128 issued up
// front in 3 chunks (12 / 4 / 8) interleaved with the 8 stage loads; staggered
// COUNTED lgkmcnt (12 -> 8 -> 0) lets chunk k+1's LDS latency hide under
// cluster k's MFMA (m201's lgkmcnt(8) trick — the piece R2-R5 were missing).
// Double-buffered: reads hit only buf cur, stages (t+1) hit only cur^1;
// tile-end vmcnt(0)+barrier is the only sync. WAR-safe: each wave's
// lgkmcnt(0) precedes cluster3 which precedes the barrier, so all reads of
// cur are complete at the barrier before cur is staged next tile.
// Swizzle: chunk ^= row&7 on GLOBAL source + read side (0 conflicts, R2-R5).
// K-accumulation order identical to R2-R5 -> bit-identical output.
// ---------------------------------------------------------------------------
#define STG_A256(t, h) { \
    ushort* d_ = As2 + ((t) & 1) * 16384 + (h) * 8192 + tid * 8; \
    GLD_LDS(aG + (size_t)((h) * 128) * 1024 + (size_t)(t) * 64, d_); \
    GLD_LDS(aG + (size_t)((h) * 128 + 64) * 1024 + (size_t)(t) * 64, d_ + 4096); }
#define STG_B256(t, h) { \
    ushort* d_ = Bs2 + ((t) & 1) * 16384 + (h) * 8192 + tid * 8; \
    GLD_LDS(bG + (size_t)((h) * 128) * 1024 + (size_t)(t) * 64, d_); \
    GLD_LDS(bG + (size_t)((h) * 128 + 64) * 1024 + (size_t)(t) * 64, d_ + 4096); }

__global__ __launch_bounds__(512, 1) void gemm_qkv(
    const ushort* __restrict__ A, const ushort* __restrict__ Bt,
    ushort* __restrict__ Qb, ushort* __restrict__ Kb, ushort* __restrict__ Vt)
{
    __shared__ ushort As2[2 * 2 * 8192];   // 64 KB
    __shared__ ushort Bs2[2 * 2 * 8192];   // 64 KB

    const int tid = threadIdx.x;
    const int lane = tid & 63;
    const int w = tid >> 6;
    const int l15 = lane & 15;
    const int quad = lane >> 4;
    const int wm = w >> 2, wn = w & 3;                 // 2M x 4N waves

    const int lin = blockIdx.y * 12 + blockIdx.x;      // 384 blocks, %8==0
    const int wg = (lin & 7) * 48 + (lin >> 3);        // XCD-chunked bijection
    const int rowBase = (wg / 12) * 256;
    const int colBase = (wg % 12) * 256;

    // staging map: thread -> (row = tid>>3 [+64 for 2nd load], chunk = tid&7)
    const int srow = tid >> 3;
    const int gsw = ((tid & 7) ^ (srow & 7)) << 3;     // pre-swizzled src chunk
    const ushort* aG = A  + (size_t)(rowBase + srow) * 1024 + gsw;
    const ushort* bG = Bt + (size_t)(colBase + srow) * 1024 + gsw;

    // read-side swizzled chunk offsets (row&7 == l15&7 for all frag rows)
    const int c0 = (quad ^ (l15 & 7)) << 3;
    const int c1 = c0 ^ 32;

    f32x4 acc[8][4];
    #pragma unroll
    for (int i_ = 0; i_ < 8; ++i_)
        #pragma unroll
        for (int j_ = 0; j_ < 4; ++j_) acc[i_][j_] = (f32x4){0.f, 0.f, 0.f, 0.f};

    // ---- prologue: stage tile 0 ----
    STG_A256(0, 0) STG_A256(0, 1) STG_B256(0, 0) STG_B256(0, 1)
    asm volatile("s_waitcnt vmcnt(0)" ::: "memory");
    __builtin_amdgcn_s_barrier();
    asm volatile("" ::: "memory");

    #pragma unroll 1
    for (int t = 0; t < 16; ++t) {
        const int cur = t & 1;
        const ushort* Ar = As2 + cur * 16384;
        const ushort* Br = Bs2 + cur * 16384;
        const ushort* a0p = Ar + (wm * 64 + l15) * 64;          // stripe0
        const ushort* a1p = a0p + 8192;                         // stripe1
        const ushort* bp  = Br + (wn >> 1) * 8192 + ((wn & 1) * 64 + l15) * 64;

        // ---- chunk1: 12 ds_reads (8 B frags + A stripe0 rows 0,1) ----
        bf16x8 b0[4], b1[4];
        #pragma unroll
        for (int ni = 0; ni < 4; ++ni) {
            b0[ni] = *(const bf16x8*)(bp + ni * 1024 + c0);
            b1[ni] = *(const bf16x8*)(bp + ni * 1024 + c1);
        }
        bf16x8 aE0 = *(const bf16x8*)(a0p + c0);
        bf16x8 aO0 = *(const bf16x8*)(a0p + c1);
        bf16x8 aE1 = *(const bf16x8*)(a0p + 1024 + c0);
        bf16x8 aO1 = *(const bf16x8*)(a0p + 1024 + c1);
        if (t + 1 < 16) { STG_A256(t + 1, 0) STG_A256(t + 1, 1) }
        // ---- chunk2: 4 ds_reads (A stripe0 rows 2,3) ----
        bf16x8 aE2 = *(const bf16x8*)(a0p + 2048 + c0);
        bf16x8 aO2 = *(const bf16x8*)(a0p + 2048 + c1);
        bf16x8 aE3 = *(const bf16x8*)(a0p + 3072 + c0);
        bf16x8 aO3 = *(const bf16x8*)(a0p + 3072 + c1);
        if (t + 1 < 16) { STG_B256(t + 1, 0) STG_B256(t + 1, 1) }
        // ---- chunk3: 8 ds_reads (A stripe1, all rows) ----
        bf16x8 s1E[4], s1O[4];
        #pragma unroll
        for (int rf = 0; rf < 4; ++rf) {
            s1E[rf] = *(const bf16x8*)(a1p + rf * 1024 + c0);
            s1O[rf] = *(const bf16x8*)(a1p + rf * 1024 + c1);
        }

        // ---- cluster1: chunk1 ready, chunks 2+3 (12) still in flight ----
        asm volatile("s_waitcnt lgkmcnt(12)" ::: "memory");
        __builtin_amdgcn_sched_barrier(0);
        __builtin_amdgcn_s_setprio(1);
        #pragma unroll
        for (int ni = 0; ni < 4; ++ni) {
            acc[0][ni] = MFMA_BF16(aE0, b0[ni], acc[0][ni]);
            acc[0][ni] = MFMA_BF16(aO0, b1[ni], acc[0][ni]);
        }
        #pragma unroll
        for (int ni = 0; ni < 4; ++ni) {
            acc[1][ni] = MFMA_BF16(aE1, b0[ni], acc[1][ni]);
            acc[1][ni] = MFMA_BF16(aO1, b1[ni], acc[1][ni]);
        }
        __builtin_amdgcn_s_setprio(0);

        // ---- cluster2: chunk2 ready (8 = chunk3 outstanding) ----
        asm volatile("s_waitcnt lgkmcnt(8)" ::: "memory");
        __builtin_amdgcn_sched_barrier(0);
        __builtin_amdgcn_s_setprio(1);
        #pragma unroll
        for (int ni = 0; ni < 4; ++ni) {
            acc[2][ni] = MFMA_BF16(aE2, b0[ni], acc[2][ni]);
            acc[2][ni] = MFMA_BF16(aO2, b1[ni], acc[2][ni]);
        }
        #pragma unroll
        for (int ni = 0; ni < 4; ++ni) {
            acc[3][ni] = MFMA_BF16(aE3, b0[ni], acc[3][ni]);
            acc[3][ni] = MFMA_BF16(aO3, b1[ni], acc[3][ni]);
        }
        __builtin_amdgcn_s_setprio(0);

        // ---- cluster3: all reads done ----
        asm volatile("s_waitcnt lgkmcnt(0)" ::: "memory");
        __builtin_amdgcn_sched_barrier(0);
        __builtin_amdgcn_s_setprio(1);
        #pragma unroll
        for (int ni = 0; ni < 4; ++ni) {
            acc[4][ni] = MFMA_BF16(s1E[0], b0[ni], acc[4][ni]);
            acc[4][ni] = MFMA_BF16(s1O[0], b1[ni], acc[4][ni]);
        }
        #pragma unroll
        for (int ni = 0; ni < 4; ++ni) {
            acc[5][ni] = MFMA_BF16(s1E[1], b0[ni], acc[5][ni]);
            acc[5][ni] = MFMA_BF16(s1O[1], b1[ni], acc[5][ni]);
        }
        #pragma unroll
        for (int ni = 0; ni < 4; ++ni) {
            acc[6][ni] = MFMA_BF16(s1E[2], b0[ni], acc[6][ni]);
            acc[6][ni] = MFMA_BF16(s1O[2], b1[ni], acc[6][ni]);
        }
        #pragma unroll
        for (int ni = 0; ni < 4; ++ni) {
            acc[7][ni] = MFMA_BF16(s1E[3], b0[ni], acc[7][ni]);
            acc[7][ni] = MFMA_BF16(s1O[3], b1[ni], acc[7][ni]);
        }
        __builtin_amdgcn_s_setprio(0);

        // ---- tile boundary: next tile staged, all reads of cur done ----
        asm volatile("s_waitcnt vmcnt(0)" ::: "memory");
        __builtin_amdgcn_s_barrier();
        asm volatile("" ::: "memory");
    }

    // ---- epilogue: seg-routed store ----
    const int seg = colBase >> 10;          // 0=Q 1=K 2=V (256-tiles don't straddle)
    if (seg == 2) {
        #pragma unroll
        for (int ri = 0; ri < 8; ++ri) {
            #pragma unroll
            for (int ni = 0; ni < 4; ++ni) {
                const int c = (colBase + wn*64 + ni*16 + l15) & 1023;
                const int h = c >> 6, d = c & 63;
                const int m = rowBase + ((ri >> 2) << 7) + wm*64 + (ri & 3)*16 + quad*4;
                const int b = m >> 11, nn = m & 2047;
                ushort4 v;
                v.x = f2bf(acc[ri][ni][0]); v.y = f2bf(acc[ri][ni][1]);
                v.z = f2bf(acc[ri][ni][2]); v.w = f2bf(acc[ri][ni][3]);
                *(ushort4*)(Vt + ((size_t)(b*16 + h)*64 + d)*2048 + nn) = v;
            }
        }
    } else {
        ushort* dst = seg ? Kb : Qb;
        // Q pre-scale: 1/sqrt(64) * log2(e)  (softmax runs in base-2 domain)
        const float sc2 = seg ? 1.0f : 0.18033688011112042f;
        #pragma unroll
        for (int ri = 0; ri < 8; ++ri) {
            #pragma unroll
            for (int ni = 0; ni < 4; ++ni) {
                const int c = (colBase + wn*64 + ni*16 + l15) & 1023;
                const int h = c >> 6, d = c & 63;
                #pragma unroll
                for (int r = 0; r < 4; ++r) {
                    const int m = rowBase + ((ri >> 2) << 7) + wm*64 + (ri & 3)*16 + quad*4 + r;
                    const int b = m >> 11, nn = m & 2047;
                    dst[((((size_t)b*16 + h)*2048 + nn) << 6) + d] = f2bf(acc[ri][ni][r] * sc2);
                }
            }
        }
    }
}

// ---------------------------------------------------------------------------
// gemm_out keeps the R4 tri-buffered 128x256 pipe (grid 256 = exact round).
// ---------------------------------------------------------------------------
#define STG32(t, Ad, Bd) { \
    GLD_LDS(aS + (size_t)(t) * 32, (Ad) + ldst); \
    GLD_LDS(bSlo + (size_t)(t) * 32, (Bd) + ldst); \
    GLD_LDS(bShi + (size_t)(t) * 32, (Bd) + 128 * 32 + ldst); }

#define GEMM_PIPE(Aptr, Btptr, NXT, NWG)                                       \
    __shared__ ushort As[3][128 * 32];                                         \
    __shared__ ushort Bs[3][256 * 32];                                         \
    const int tid = threadIdx.x;                                               \
    const int lane = tid & 63;                                                 \
    const int w = tid >> 6;                                                    \
    const int l15 = lane & 15;                                                 \
    const int quad = lane >> 4;                                                \
    const int wm = w >> 2, wn = w & 3;                                         \
    const int lin = blockIdx.y * (NXT) + blockIdx.x;                           \
    const int wg = (lin & 7) * ((NWG) >> 3) + (lin >> 3);                      \
    const int rowBase = (wg / (NXT)) * 128;                                    \
    const int colBase = (wg % (NXT)) * 256;                                    \
    const int sr = tid >> 2, sc = tid & 3;                                     \
    const int ldst = sr * 32 + sc * 8;                                         \
    const int gsw = (sc ^ ((sr >> 1) & 3)) << 3;                               \
    const ushort* aS   = (Aptr)  + (size_t)(rowBase + sr) * 1024 + gsw;        \
    const ushort* bSlo = (Btptr) + (size_t)(colBase + sr) * 1024 + gsw;        \
    const ushort* bShi = bSlo + (size_t)128 * 1024;                            \
    const int co = ((quad ^ ((l15 >> 1) & 3)) << 3);                           \
    f32x4 acc[4][4];                                                           \
    _Pragma("unroll")                                                          \
    for (int i_ = 0; i_ < 4; ++i_)                                             \
        _Pragma("unroll")                                                      \
        for (int j_ = 0; j_ < 4; ++j_) acc[i_][j_] = (f32x4){0.f, 0.f, 0.f, 0.f}; \
    ushort *Acur = As[0], *Anxt = As[1], *Apre = As[2];                        \
    ushort *Bcur = Bs[0], *Bnxt = Bs[1], *Bpre = Bs[2];                        \
    STG32(0, Acur, Bcur)                                                       \
    STG32(1, Anxt, Bnxt)                                                       \
    asm volatile("s_waitcnt vmcnt(3)" ::: "memory");                           \
    __builtin_amdgcn_s_barrier();                                              \
    asm volatile("" ::: "memory");                                             \
    _Pragma("unroll 1")                                                        \
    for (int u = 0; u < 32; ++u) {                                             \
        if (u + 2 < 32) { STG32(u + 2, Apre, Bpre) }                           \
        const ushort* aC = Acur + (wm * 64 + l15) * 32;                        \
        const ushort* bC = Bcur + (wn * 64 + l15) * 32;                        \
        bf16x8 aF[4], bF[4];                                                   \
        _Pragma("unroll")                                                      \
        for (int ni = 0; ni < 4; ++ni)                                         \
            bF[ni] = *(const bf16x8*)(bC + ni * 512 + co);                     \
        _Pragma("unroll")                                                      \
        for (int mi = 0; mi < 4; ++mi)                                         \
            aF[mi] = *(const bf16x8*)(aC + mi * 512 + co);                     \
        __builtin_amdgcn_s_setprio(1);                                         \
        _Pragma("unroll")                                                      \
        for (int mi = 0; mi < 4; ++mi)                                         \
            _Pragma("unroll")                                                  \
            for (int ni = 0; ni < 4; ++ni)                                     \
                acc[mi][ni] = __builtin_amdgcn_mfma_f32_16x16x32_bf16(         \
                    aF[mi], bF[ni], acc[mi][ni], 0, 0, 0);                     \
        __builtin_amdgcn_s_setprio(0);                                         \
        if (u < 30)       { asm volatile("s_waitcnt vmcnt(3)" ::: "memory"); } \
        else if (u == 30) { asm volatile("s_waitcnt vmcnt(0)" ::: "memory"); } \
        if (u < 31) {                                                          \
            __builtin_amdgcn_s_barrier();                                      \
            asm volatile("" ::: "memory");                                     \
        }                                                                      \
        ushort* tA = Acur; Acur = Anxt; Anxt = Apre; Apre = tA;                \
        ushort* tB = Bcur; Bcur = Bnxt; Bnxt = Bpre; Bpre = tB;                \
    }

__global__ __launch_bounds__(512, 4) void gemm_out(
    const ushort* __restrict__ A, const ushort* __restrict__ Bt,
    const float* __restrict__ bo, float* __restrict__ out)
{
    GEMM_PIPE(A, Bt, 4, 256)

    #pragma unroll
    for (int mi = 0; mi < 4; ++mi) {
        #pragma unroll
        for (int ni = 0; ni < 4; ++ni) {
            const int n = colBase + wn*64 + ni*16 + l15;
            const float bb = bo[n];
            #pragma unroll
            for (int r = 0; r < 4; ++r) {
                const int m = rowBase + wm*64 + mi*16 + quad*4 + r;
                out[(size_t)m * 1024 + n] = acc[mi][ni][r] + bb;
            }
        }
    }
}

// ---------------------------------------------------------------------------
// Flash attention v5: unpaired q-tiles (grid 1024, qt-descending dispatch),
// double-buffered LDS K/V, S^T trick, skip-rescale on no-new-max.
// Block = 4 waves x 32 q-rows = one 128-row q-tile.
// ---------------------------------------------------------------------------
__device__ __forceinline__ bf16x8 lds_frag(const ushort* S, int row, int chunk) {
    return *(const bf16x8*)(S + row * 64 + ((chunk ^ (row & 7)) << 3));
}

__global__ __launch_bounds__(256, 2) void flash_mfma(
    const ushort* __restrict__ Qb,
    const ushort* __restrict__ Kb,
    const ushort* __restrict__ Vt,
    ushort* __restrict__ Ob)
{
    __shared__ ushort Ks[2][4096];
    __shared__ ushort Vs[2][4096];
    __shared__ ushort PsAll[4][32][72];

    const int tid = threadIdx.x;
    const int w = tid >> 6;
    const int lane = tid & 63;
    const int l15 = lane & 15;
    const int quad = lane >> 4;
    ushort (*Ps)[72] = PsAll[w];

    const int blk = blockIdx.x;
    const int bh = ((blk & 7) << 3) | ((blk >> 3) & 7);
    const int qt = 15 - (blk >> 6);
    const int nt = 2 * qt + 2;
    const int rb0 = (qt << 7) + w * 32;

    const int sr0 = tid >> 3, sr1 = sr0 + 32;
    const int cg0 = (tid & 7) ^ (sr0 & 7);
    const int cg1 = (tid & 7) ^ (sr1 & 7);
    const ushort* kgb = Kb + (size_t)bh * 131072;
    const ushort* vgb = Vt + (size_t)bh * 131072;

    bf16x8 qf[2][2];
    #pragma unroll
    for (int mi = 0; mi < 2; ++mi) {
        const ushort* qp = Qb + ((size_t)bh * 2048 + rb0 + mi*16 + l15) * 64 + quad * 8;
        qf[mi][0] = *(const bf16x8*)qp;
        qf[mi][1] = *(const bf16x8*)(qp + 32);
    }

    bf16x8 bones;
    #pragma unroll
    for (int j = 0; j < 8; ++j) bones[j] = (short)0x3F80;   // bf16 1.0

    float m_r[2];
    f32x4 o[2][4], lacc[2];
    #pragma unroll
    for (int mi = 0; mi < 2; ++mi) {
        m_r[mi] = -INFINITY;
        lacc[mi] = (f32x4){0.f, 0.f, 0.f, 0.f};
        #pragma unroll
        for (int nb = 0; nb < 4; ++nb) o[mi][nb] = (f32x4){0.f, 0.f, 0.f, 0.f};
    }

    GLD_LDS(kgb + sr0*64 + cg0*8, &Ks[0][tid*8]);
    GLD_LDS(kgb + sr1*64 + cg1*8, &Ks[0][tid*8 + 2048]);
    GLD_LDS(vgb + (size_t)sr0*2048 + cg0*8, &Vs[0][tid*8]);
    GLD_LDS(vgb + (size_t)sr1*2048 + cg1*8, &Vs[0][tid*8 + 2048]);

    for (int t = 0; t < nt; ++t) {
        __syncthreads();
        const int cur = t & 1;
        if (t + 1 < nt) {
            const int jn = t + 1;
            ushort* kd = &Ks[cur ^ 1][tid * 8];
            ushort* vd = &Vs[cur ^ 1][tid * 8];
            GLD_LDS(kgb + (size_t)jn*4096 + sr0*64 + cg0*8, kd);
            GLD_LDS(kgb + (size_t)jn*4096 + sr1*64 + cg1*8, kd + 2048);
            GLD_LDS(vgb + (size_t)sr0*2048 + jn*64 + cg0*8, vd);
            GLD_LDS(vgb + (size_t)sr1*2048 + jn*64 + cg1*8, vd + 2048);
        }
        const int j0 = t << 6;
        if (j0 > rb0 + 31) continue;

        const ushort* Ksb = Ks[cur];
        const ushort* Vsb = Vs[cur];

        f32x4 St[2][4];
        #pragma unroll
        for (int kb = 0; kb < 4; ++kb) {
            bf16x8 ka = lds_frag(Ksb, kb*16 + l15, quad);
            bf16x8 kc = lds_frag(Ksb, kb*16 + l15, quad + 4);
            #pragma unroll
            for (int mi = 0; mi < 2; ++mi) {
                f32x4 s = (f32x4){0.f, 0.f, 0.f, 0.f};
                s = MFMA_BF16(ka, qf[mi][0], s);
                s = MFMA_BF16(kc, qf[mi][1], s);
                St[mi][kb] = s;
            }
        }

        #pragma unroll
        for (int mi = 0; mi < 2; ++mi) {
            const int qrow = rb0 + mi*16 + l15;
            if (j0 + 63 > rb0 + mi*16) {
                #pragma unroll
                for (int kb = 0; kb < 4; ++kb) {
                    const int kbase = j0 + kb*16 + quad*4;
                    #pragma unroll
                    for (int r = 0; r < 4; ++r)
                        if (kbase + r > qrow) St[mi][kb][r] = -INFINITY;
                }
            }
            f32x4 mv = St[mi][0];
            #pragma unroll
            for (int kb = 1; kb < 4; ++kb)
                #pragma unroll
                for (int r = 0; r < 4; ++r) mv[r] = fmaxf(mv[r], St[mi][kb][r]);
            float mx = fmaxf(fmaxf(mv[0], mv[1]), fmaxf(mv[2], mv[3]));
            mx = fmaxf(mx, __shfl_xor(mx, 16));
            mx = fmaxf(mx, __shfl_xor(mx, 32));
            const float mold = m_r[mi];
            const float mnew = fmaxf(mold, mx);
            if (__any(mnew > mold)) {
                m_r[mi] = mnew;
                const float corr = __builtin_amdgcn_exp2f(mold - mnew);
                float ct[4];
                #pragma unroll
                for (int r = 0; r < 4; ++r) ct[r] = __shfl(corr, quad*4 + r);
                #pragma unroll
                for (int r = 0; r < 4; ++r) lacc[mi][r] *= ct[r];
                #pragma unroll
                for (int nb = 0; nb < 4; ++nb)
                    #pragma unroll
                    for (int r = 0; r < 4; ++r) o[mi][nb][r] *= ct[r];
            }
            #pragma unroll
            for (int kb = 0; kb < 4; ++kb)
                #pragma unroll
                for (int r = 0; r < 4; ++r)
                    St[mi][kb][r] = __builtin_amdgcn_exp2f(St[mi][kb][r] - mnew);
            #pragma unroll
            for (int kb = 0; kb < 4; ++kb) {
                union { float f; unsigned u; } c0_, c1_, c2_, c3_;
                c0_.f = St[mi][kb][0]; c1_.f = St[mi][kb][1];
                c2_.f = St[mi][kb][2]; c3_.f = St[mi][kb][3];
                uint2 pk;
                pk.x = (c0_.u >> 16) | (c1_.u & 0xFFFF0000u);
                pk.y = (c2_.u >> 16) | (c3_.u & 0xFFFF0000u);
                *(uint2*)&Ps[mi*16 + l15][kb*16 + quad*4] = pk;
            }
        }

        bf16x8 pf[2][2];
        #pragma unroll
        for (int mi = 0; mi < 2; ++mi) {
            pf[mi][0] = *(const bf16x8*)&Ps[mi*16 + l15][quad * 8];
            pf[mi][1] = *(const bf16x8*)&Ps[mi*16 + l15][32 + quad * 8];
        }
        #pragma unroll
        for (int mi = 0; mi < 2; ++mi) {
            lacc[mi] = MFMA_BF16(pf[mi][0], bones, lacc[mi]);
            lacc[mi] = MFMA_BF16(pf[mi][1], bones, lacc[mi]);
        }
        #pragma unroll
        for (int nb = 0; nb < 4; ++nb) {
            bf16x8 va = lds_frag(Vsb, nb*16 + l15, quad);
            bf16x8 vc = lds_frag(Vsb, nb*16 + l15, quad + 4);
            #pragma unroll
            for (int mi = 0; mi < 2; ++mi) {
                o[mi][nb] = MFMA_BF16(pf[mi][0], va, o[mi][nb]);
                o[mi][nb] = MFMA_BF16(pf[mi][1], vc, o[mi][nb]);
            }
        }
    }

    const int b = bh >> 4, h = bh & 15;
    #pragma unroll
    for (int mi = 0; mi < 2; ++mi)
        #pragma unroll
        for (int r = 0; r < 4; ++r) {
            const int ig = rb0 + mi*16 + quad*4 + r;
            const float inv = 1.f / lacc[mi][r];
            ushort* op = Ob + ((size_t)(b * 2048 + ig)) * 1024 + h * 64 + l15;
            #pragma unroll
            for (int nb = 0; nb < 4; ++nb)
                op[nb * 16] = f2bf(o[mi][nb][r] * inv);
        }
}

// ---------------------------------------------------------------------------
extern "C" void kernel_launch(void* const* d_in, const int* in_sizes, int n_in,
                              void* d_out, int out_size, void* d_ws, size_t ws_size,
                              hipStream_t stream) {
    const float* x   = (const float*)d_in[0];
    const float* Wq  = (const float*)d_in[1];
    const float* Wkv = (const float*)d_in[2];
    const float* Wo  = (const float*)d_in[3];
    const float* bo  = (const float*)d_in[4];
    float* out = (float*)d_out;

    const size_t SEG = (size_t)8388608 * 2;   // 16 MB per bf16 [8192x1024]
    char* ws = (char*)d_ws;
    ushort* xb = (ushort*)(ws);
    ushort* Qb = (ushort*)(ws + SEG);
    ushort* Kb = (ushort*)(ws + SEG * 2);
    ushort* Vt = (ushort*)(ws + SEG * 3);     // [bh*64+d][2048]
    ushort* Ob = (ushort*)(ws + SEG * 4);
    ushort* Wt = (ushort*)(ws + SEG * 5);     // [4096][1024] bf16

    convert_x<<<dim3(4096), 256, 0, stream>>>(x, xb);
    prep_w<<<dim3(256), 256, 0, stream>>>(Wq, Wkv, Wo, Wt);
    gemm_qkv<<<dim3(12, 32), 512, 0, stream>>>(xb, Wt, Qb, Kb, Vt);
    flash_mfma<<<dim3(1024), 256, 0, stream>>>(Qb, Kb, Vt, Ob);
    gemm_out<<<dim3(4, 64), 512, 0, stream>>>(Ob, Wt + (size_t)3072 * 1024, bo, out);
}

// Round 7
// 253.470 us; speedup vs baseline: 1.0578x; 1.0578x over previous
//
#include <hip/hip_runtime.h>
#include <hip/hip_bf16.h>
#include <math.h>

typedef __attribute__((ext_vector_type(8))) short bf16x8;
typedef __attribute__((ext_vector_type(4))) float f32x4;

static __device__ inline ushort f2bf(float f) {
    union { float f; unsigned u; } v; v.f = f;
    unsigned r = (v.u + 0x7fff + ((v.u >> 16) & 1)) >> 16;   // RNE
    return (ushort)r;
}

#define GLD_LDS(g, l) \
    __builtin_amdgcn_global_load_lds( \
        (const __attribute__((address_space(1))) void*)(g), \
        (__attribute__((address_space(3))) void*)(l), 16, 0, 0)

#define MFMA_BF16(a, b, c) __builtin_amdgcn_mfma_f32_16x16x32_bf16((a), (b), (c), 0, 0, 0)

// ---------------------------------------------------------------------------
// x fp32 -> bf16
// ---------------------------------------------------------------------------
__global__ __launch_bounds__(256) void convert_x(
    const float* __restrict__ x, ushort* __restrict__ xb)
{
    const size_t i = ((size_t)blockIdx.x * 256 + threadIdx.x) * 8;
    float4 a = *(const float4*)(x + i);
    float4 b = *(const float4*)(x + i + 4);
    bf16x8 t;
    t[0] = (short)f2bf(a.x); t[1] = (short)f2bf(a.y);
    t[2] = (short)f2bf(a.z); t[3] = (short)f2bf(a.w);
    t[4] = (short)f2bf(b.x); t[5] = (short)f2bf(b.y);
    t[6] = (short)f2bf(b.z); t[7] = (short)f2bf(b.w);
    *(bf16x8*)(xb + i) = t;
}

// ---------------------------------------------------------------------------
// Weights fp32 [K][N] -> Wt bf16 [4096][1024] transposed
// ---------------------------------------------------------------------------
__global__ __launch_bounds__(256) void prep_w(
    const float* __restrict__ Wq, const float* __restrict__ Wkv,
    const float* __restrict__ Wo, ushort* __restrict__ Wt)
{
    const int w = threadIdx.x >> 6;
    const int lane = threadIdx.x & 63;
    const int tile = blockIdx.x * 4 + w;
    const int r0 = (tile >> 4) << 6;
    const int k0 = (tile & 15) << 6;

    const float* src; int ld, c0;
    if (r0 < 1024)      { src = Wq;  ld = 1024; c0 = r0; }
    else if (r0 < 3072) { src = Wkv; ld = 2048; c0 = r0 - 1024; }
    else                { src = Wo;  ld = 1024; c0 = r0 - 3072; }

    ushort v[64];
    #pragma unroll
    for (int k = 0; k < 64; ++k)
        v[k] = f2bf(src[(size_t)(k0 + k) * ld + c0 + lane]);

    ushort* dst = Wt + (size_t)(r0 + lane) * 1024 + k0;
    #pragma unroll
    for (int k = 0; k < 64; k += 8) {
        bf16x8 t;
        #pragma unroll
        for (int j = 0; j < 8; ++j) t[j] = (short)v[k + j];
        *(bf16x8*)(dst + k) = t;
    }
}

// ---------------------------------------------------------------------------
// gemm_qkv: 256(M)x384(N) tile, BK=32, 512 thr / 8 waves (2M x 4N),
// per-wave 128x96 = 8x6 frags (298 B LDS-read per MFMA, best ratio).
// Grid = 32x8 = 256 blocks = EXACTLY one round at 1 block/CU (no tail —
// R5's schedule gain was eaten by its 1.5-round tail; this removes it).
// Simple R4-style loop, double-buffered (80 KB LDS):
//   stage(t+1 -> other buf) first; read 6 B-frags; stream 8x(A-read+6 MFMA);
//   vmcnt(0); one barrier.  WAR: buf (t+1)&1 was read in step t-1, those
//   reads were consumed by MFMAs before the t-1-end barrier. RAW: stage for
//   t+1 issued at t start, covered by ~2000cyc of compute + vmcnt(0).
// Swizzle: R4's measured-conflict-free BK=32 form, chunk ^= (row>>1)&3,
// applied on the GLOBAL source (gload_lds writes linearly) and on reads.
// K-accumulation ascending 32-chunks -> bit-identical to R4.
// ---------------------------------------------------------------------------
#define STG_A96(t) { ushort* d_ = As2 + ((t) & 1) * 8192 + ldst; \
    GLD_LDS(aG + (size_t)(t) * 32, d_); \
    GLD_LDS(aG + (size_t)131072 + (size_t)(t) * 32, d_ + 4096); }
#define STG_B96(t) { ushort* d_ = Bs2 + ((t) & 1) * 12288 + ldst; \
    GLD_LDS(bG + (size_t)(t) * 32, d_); \
    GLD_LDS(bG + (size_t)131072 + (size_t)(t) * 32, d_ + 4096); \
    GLD_LDS(bG + (size_t)262144 + (size_t)(t) * 32, d_ + 8192); }

__global__ __launch_bounds__(512, 2) void gemm_qkv(
    const ushort* __restrict__ A, const ushort* __restrict__ Bt,
    ushort* __restrict__ Qb, ushort* __restrict__ Kb, ushort* __restrict__ Vt)
{
    __shared__ ushort As2[2 * 8192];    // 2 x 256x32 = 32 KB
    __shared__ ushort Bs2[2 * 12288];   // 2 x 384x32 = 48 KB

    const int tid = threadIdx.x;
    const int lane = tid & 63;
    const int w = tid >> 6;
    const int l15 = lane & 15;
    const int quad = lane >> 4;
    const int wm = w >> 2, wn = w & 3;                 // 2M x 4N waves

    const int lin = blockIdx.y * 8 + blockIdx.x;       // 256 blocks, %8==0
    const int wg = (lin & 7) * 32 + (lin >> 3);        // XCD-chunked bijection
    const int rowBase = (wg >> 3) * 256;               // 32 M-tiles
    const int colBase = (wg & 7) * 384;                // 8 N-tiles

    // staging: 4 thr/row (row = 32 bf16 = 64 B = 4 chunks of 16 B)
    const int sr = tid >> 2, sc = tid & 3;             // sr 0..127
    const int ldst = sr * 32 + sc * 8;
    const int gsw = (sc ^ ((sr >> 1) & 3)) << 3;       // pre-swizzled source
    const ushort* aG = A  + (size_t)(rowBase + sr) * 1024 + gsw;
    const ushort* bG = Bt + (size_t)(colBase + sr) * 1024 + gsw;

    // read-side swizzled chunk (row>>1 & 3 == l15>>1 & 3 for all frag rows)
    const int co = (quad ^ ((l15 >> 1) & 3)) << 3;

    f32x4 acc[8][6];
    #pragma unroll
    for (int i_ = 0; i_ < 8; ++i_)
        #pragma unroll
        for (int j_ = 0; j_ < 6; ++j_) acc[i_][j_] = (f32x4){0.f, 0.f, 0.f, 0.f};

    // ---- prologue: stage tile 0 ----
    STG_A96(0) STG_B96(0)
    asm volatile("s_waitcnt vmcnt(0)" ::: "memory");
    __builtin_amdgcn_s_barrier();
    asm volatile("" ::: "memory");

    #pragma unroll 1
    for (int t = 0; t < 32; ++t) {
        const int cur = t & 1;
        if (t + 1 < 32) { STG_A96(t + 1) STG_B96(t + 1) }

        const ushort* aRd = As2 + cur * 8192  + (wm * 128 + l15) * 32;
        const ushort* bRd = Bs2 + cur * 12288 + (wn * 96 + l15) * 32;

        bf16x8 bF[6];
        #pragma unroll
        for (int ni = 0; ni < 6; ++ni)
            bF[ni] = *(const bf16x8*)(bRd + ni * 512 + co);

        __builtin_amdgcn_s_setprio(1);
        #pragma unroll
        for (int ri = 0; ri < 8; ++ri) {
            bf16x8 aF = *(const bf16x8*)(aRd + ri * 512 + co);
            #pragma unroll
            for (int ni = 0; ni < 6; ++ni)
                acc[ri][ni] = MFMA_BF16(aF, bF[ni], acc[ri][ni]);
        }
        __builtin_amdgcn_s_setprio(0);

        asm volatile("s_waitcnt vmcnt(0)" ::: "memory");
        __builtin_amdgcn_s_barrier();
        asm volatile("" ::: "memory");
    }

    // ---- epilogue: per-frag seg routing (384-tiles straddle Q/K/V; 16-col
    // frags never straddle since 1024 % 16 == 0) ----
    const float qsc = 0.18033688011112042f;   // 1/sqrt(64) * log2(e)
    #pragma unroll
    for (int ri = 0; ri < 8; ++ri) {
        #pragma unroll
        for (int ni = 0; ni < 6; ++ni) {
            const int c = colBase + wn * 96 + ni * 16 + l15;
            const int seg = c >> 10;
            const int h = (c & 1023) >> 6, d = c & 63;
            if (seg == 2) {
                const int m = rowBase + wm * 128 + ri * 16 + quad * 4;
                const int b = m >> 11, nn = m & 2047;
                ushort4 v;
                v.x = f2bf(acc[ri][ni][0]); v.y = f2bf(acc[ri][ni][1]);
                v.z = f2bf(acc[ri][ni][2]); v.w = f2bf(acc[ri][ni][3]);
                *(ushort4*)(Vt + ((size_t)(b * 16 + h) * 64 + d) * 2048 + nn) = v;
            } else {
                ushort* dst = seg ? Kb : Qb;
                const float sc2 = seg ? 1.0f : qsc;
                #pragma unroll
                for (int r = 0; r < 4; ++r) {
                    const int m = rowBase + wm * 128 + ri * 16 + quad * 4 + r;
                    const int b = m >> 11, nn = m & 2047;
                    dst[((((size_t)b * 16 + h) * 2048 + nn) << 6) + d] = f2bf(acc[ri][ni][r] * sc2);
                }
            }
        }
    }
}

// ---------------------------------------------------------------------------
// gemm_out keeps the R4 tri-buffered 128x256 pipe (grid 256 = exact round).
// ---------------------------------------------------------------------------
#define STG32(t, Ad, Bd) { \
    GLD_LDS(aS + (size_t)(t) * 32, (Ad) + ldst); \
    GLD_LDS(bSlo + (size_t)(t) * 32, (Bd) + ldst); \
    GLD_LDS(bShi + (size_t)(t) * 32, (Bd) + 128 * 32 + ldst); }

#define GEMM_PIPE(Aptr, Btptr, NXT, NWG)                                       \
    __shared__ ushort As[3][128 * 32];                                         \
    __shared__ ushort Bs[3][256 * 32];                                         \
    const int tid = threadIdx.x;                                               \
    const int lane = tid & 63;                                                 \
    const int w = tid >> 6;                                                    \
    const int l15 = lane & 15;                                                 \
    const int quad = lane >> 4;                                                \
    const int wm = w >> 2, wn = w & 3;                                         \
    const int lin = blockIdx.y * (NXT) + blockIdx.x;                           \
    const int wg = (lin & 7) * ((NWG) >> 3) + (lin >> 3);                      \
    const int rowBase = (wg / (NXT)) * 128;                                    \
    const int colBase = (wg % (NXT)) * 256;                                    \
    const int sr = tid >> 2, sc = tid & 3;                                     \
    const int ldst = sr * 32 + sc * 8;                                         \
    const int gsw = (sc ^ ((sr >> 1) & 3)) << 3;                               \
    const ushort* aS   = (Aptr)  + (size_t)(rowBase + sr) * 1024 + gsw;        \
    const ushort* bSlo = (Btptr) + (size_t)(colBase + sr) * 1024 + gsw;        \
    const ushort* bShi = bSlo + (size_t)128 * 1024;                            \
    const int co = ((quad ^ ((l15 >> 1) & 3)) << 3);                           \
    f32x4 acc[4][4];                                                           \
    _Pragma("unroll")                                                          \
    for (int i_ = 0; i_ < 4; ++i_)                                             \
        _Pragma("unroll")                                                      \
        for (int j_ = 0; j_ < 4; ++j_) acc[i_][j_] = (f32x4){0.f, 0.f, 0.f, 0.f}; \
    ushort *Acur = As[0], *Anxt = As[1], *Apre = As[2];                        \
    ushort *Bcur = Bs[0], *Bnxt = Bs[1], *Bpre = Bs[2];                        \
    STG32(0, Acur, Bcur)                                                       \
    STG32(1, Anxt, Bnxt)                                                       \
    asm volatile("s_waitcnt vmcnt(3)" ::: "memory");                           \
    __builtin_amdgcn_s_barrier();                                              \
    asm volatile("" ::: "memory");                                             \
    _Pragma("unroll 1")                                                        \
    for (int u = 0; u < 32; ++u) {                                             \
        if (u + 2 < 32) { STG32(u + 2, Apre, Bpre) }                           \
        const ushort* aC = Acur + (wm * 64 + l15) * 32;                        \
        const ushort* bC = Bcur + (wn * 64 + l15) * 32;                        \
        bf16x8 aF[4], bF[4];                                                   \
        _Pragma("unroll")                                                      \
        for (int ni = 0; ni < 4; ++ni)                                         \
            bF[ni] = *(const bf16x8*)(bC + ni * 512 + co);                     \
        _Pragma("unroll")                                                      \
        for (int mi = 0; mi < 4; ++mi)                                         \
            aF[mi] = *(const bf16x8*)(aC + mi * 512 + co);                     \
        __builtin_amdgcn_s_setprio(1);                                         \
        _Pragma("unroll")                                                      \
        for (int mi = 0; mi < 4; ++mi)                                         \
            _Pragma("unroll")                                                  \
            for (int ni = 0; ni < 4; ++ni)                                     \
                acc[mi][ni] = __builtin_amdgcn_mfma_f32_16x16x32_bf16(         \
                    aF[mi], bF[ni], acc[mi][ni], 0, 0, 0);                     \
        __builtin_amdgcn_s_setprio(0);                                         \
        if (u < 30)       { asm volatile("s_waitcnt vmcnt(3)" ::: "memory"); } \
        else if (u == 30) { asm volatile("s_waitcnt vmcnt(0)" ::: "memory"); } \
        if (u < 31) {                                                          \
            __builtin_amdgcn_s_barrier();                                      \
            asm volatile("" ::: "memory");                                     \
        }                                                                      \
        ushort* tA = Acur; Acur = Anxt; Anxt = Apre; Apre = tA;                \
        ushort* tB = Bcur; Bcur = Bnxt; Bnxt = Bpre; Bpre = tB;                \
    }

__global__ __launch_bounds__(512, 4) void gemm_out(
    const ushort* __restrict__ A, const ushort* __restrict__ Bt,
    const float* __restrict__ bo, float* __restrict__ out)
{
    GEMM_PIPE(A, Bt, 4, 256)

    #pragma unroll
    for (int mi = 0; mi < 4; ++mi) {
        #pragma unroll
        for (int ni = 0; ni < 4; ++ni) {
            const int n = colBase + wn*64 + ni*16 + l15;
            const float bb = bo[n];
            #pragma unroll
            for (int r = 0; r < 4; ++r) {
                const int m = rowBase + wm*64 + mi*16 + quad*4 + r;
                out[(size_t)m * 1024 + n] = acc[mi][ni][r] + bb;
            }
        }
    }
}

// ---------------------------------------------------------------------------
// Flash attention v5: unpaired q-tiles (grid 1024, qt-descending dispatch),
// double-buffered LDS K/V, S^T trick, skip-rescale on no-new-max.
// Block = 4 waves x 32 q-rows = one 128-row q-tile.
// ---------------------------------------------------------------------------
__device__ __forceinline__ bf16x8 lds_frag(const ushort* S, int row, int chunk) {
    return *(const bf16x8*)(S + row * 64 + ((chunk ^ (row & 7)) << 3));
}

__global__ __launch_bounds__(256, 2) void flash_mfma(
    const ushort* __restrict__ Qb,
    const ushort* __restrict__ Kb,
    const ushort* __restrict__ Vt,
    ushort* __restrict__ Ob)
{
    __shared__ ushort Ks[2][4096];
    __shared__ ushort Vs[2][4096];
    __shared__ ushort PsAll[4][32][72];

    const int tid = threadIdx.x;
    const int w = tid >> 6;
    const int lane = tid & 63;
    const int l15 = lane & 15;
    const int quad = lane >> 4;
    ushort (*Ps)[72] = PsAll[w];

    const int blk = blockIdx.x;
    const int bh = ((blk & 7) << 3) | ((blk >> 3) & 7);
    const int qt = 15 - (blk >> 6);
    const int nt = 2 * qt + 2;
    const int rb0 = (qt << 7) + w * 32;

    const int sr0 = tid >> 3, sr1 = sr0 + 32;
    const int cg0 = (tid & 7) ^ (sr0 & 7);
    const int cg1 = (tid & 7) ^ (sr1 & 7);
    const ushort* kgb = Kb + (size_t)bh * 131072;
    const ushort* vgb = Vt + (size_t)bh * 131072;

    bf16x8 qf[2][2];
    #pragma unroll
    for (int mi = 0; mi < 2; ++mi) {
        const ushort* qp = Qb + ((size_t)bh * 2048 + rb0 + mi*16 + l15) * 64 + quad * 8;
        qf[mi][0] = *(const bf16x8*)qp;
        qf[mi][1] = *(const bf16x8*)(qp + 32);
    }

    bf16x8 bones;
    #pragma unroll
    for (int j = 0; j < 8; ++j) bones[j] = (short)0x3F80;   // bf16 1.0

    float m_r[2];
    f32x4 o[2][4], lacc[2];
    #pragma unroll
    for (int mi = 0; mi < 2; ++mi) {
        m_r[mi] = -INFINITY;
        lacc[mi] = (f32x4){0.f, 0.f, 0.f, 0.f};
        #pragma unroll
        for (int nb = 0; nb < 4; ++nb) o[mi][nb] = (f32x4){0.f, 0.f, 0.f, 0.f};
    }

    GLD_LDS(kgb + sr0*64 + cg0*8, &Ks[0][tid*8]);
    GLD_LDS(kgb + sr1*64 + cg1*8, &Ks[0][tid*8 + 2048]);
    GLD_LDS(vgb + (size_t)sr0*2048 + cg0*8, &Vs[0][tid*8]);
    GLD_LDS(vgb + (size_t)sr1*2048 + cg1*8, &Vs[0][tid*8 + 2048]);

    for (int t = 0; t < nt; ++t) {
        __syncthreads();
        const int cur = t & 1;
        if (t + 1 < nt) {
            const int jn = t + 1;
            ushort* kd = &Ks[cur ^ 1][tid * 8];
            ushort* vd = &Vs[cur ^ 1][tid * 8];
            GLD_LDS(kgb + (size_t)jn*4096 + sr0*64 + cg0*8, kd);
            GLD_LDS(kgb + (size_t)jn*4096 + sr1*64 + cg1*8, kd + 2048);
            GLD_LDS(vgb + (size_t)sr0*2048 + jn*64 + cg0*8, vd);
            GLD_LDS(vgb + (size_t)sr1*2048 + jn*64 + cg1*8, vd + 2048);
        }
        const int j0 = t << 6;
        if (j0 > rb0 + 31) continue;

        const ushort* Ksb = Ks[cur];
        const ushort* Vsb = Vs[cur];

        f32x4 St[2][4];
        #pragma unroll
        for (int kb = 0; kb < 4; ++kb) {
            bf16x8 ka = lds_frag(Ksb, kb*16 + l15, quad);
            bf16x8 kc = lds_frag(Ksb, kb*16 + l15, quad + 4);
            #pragma unroll
            for (int mi = 0; mi < 2; ++mi) {
                f32x4 s = (f32x4){0.f, 0.f, 0.f, 0.f};
                s = MFMA_BF16(ka, qf[mi][0], s);
                s = MFMA_BF16(kc, qf[mi][1], s);
                St[mi][kb] = s;
            }
        }

        #pragma unroll
        for (int mi = 0; mi < 2; ++mi) {
            const int qrow = rb0 + mi*16 + l15;
            if (j0 + 63 > rb0 + mi*16) {
                #pragma unroll
                for (int kb = 0; kb < 4; ++kb) {
                    const int kbase = j0 + kb*16 + quad*4;
                    #pragma unroll
                    for (int r = 0; r < 4; ++r)
                        if (kbase + r > qrow) St[mi][kb][r] = -INFINITY;
                }
            }
            f32x4 mv = St[mi][0];
            #pragma unroll
            for (int kb = 1; kb < 4; ++kb)
                #pragma unroll
                for (int r = 0; r < 4; ++r) mv[r] = fmaxf(mv[r], St[mi][kb][r]);
            float mx = fmaxf(fmaxf(mv[0], mv[1]), fmaxf(mv[2], mv[3]));
            mx = fmaxf(mx, __shfl_xor(mx, 16));
            mx = fmaxf(mx, __shfl_xor(mx, 32));
            const float mold = m_r[mi];
            const float mnew = fmaxf(mold, mx);
            if (__any(mnew > mold)) {
                m_r[mi] = mnew;
                const float corr = __builtin_amdgcn_exp2f(mold - mnew);
                float ct[4];
                #pragma unroll
                for (int r = 0; r < 4; ++r) ct[r] = __shfl(corr, quad*4 + r);
                #pragma unroll
                for (int r = 0; r < 4; ++r) lacc[mi][r] *= ct[r];
                #pragma unroll
                for (int nb = 0; nb < 4; ++nb)
                    #pragma unroll
                    for (int r = 0; r < 4; ++r) o[mi][nb][r] *= ct[r];
            }
            #pragma unroll
            for (int kb = 0; kb < 4; ++kb)
                #pragma unroll
                for (int r = 0; r < 4; ++r)
                    St[mi][kb][r] = __builtin_amdgcn_exp2f(St[mi][kb][r] - mnew);
            #pragma unroll
            for (int kb = 0; kb < 4; ++kb) {
                union { float f; unsigned u; } c0_, c1_, c2_, c3_;
                c0_.f = St[mi][kb][0]; c1_.f = St[mi][kb][1];
                c2_.f = St[mi][kb][2]; c3_.f = St[mi][kb][3];
                uint2 pk;
                pk.x = (c0_.u >> 16) | (c1_.u & 0xFFFF0000u);
                pk.y = (c2_.u >> 16) | (c3_.u & 0xFFFF0000u);
                *(uint2*)&Ps[mi*16 + l15][kb*16 + quad*4] = pk;
            }
        }

        bf16x8 pf[2][2];
        #pragma unroll
        for (int mi = 0; mi < 2; ++mi) {
            pf[mi][0] = *(const bf16x8*)&Ps[mi*16 + l15][quad * 8];
            pf[mi][1] = *(const bf16x8*)&Ps[mi*16 + l15][32 + quad * 8];
        }
        #pragma unroll
        for (int mi = 0; mi < 2; ++mi) {
            lacc[mi] = MFMA_BF16(pf[mi][0], bones, lacc[mi]);
            lacc[mi] = MFMA_BF16(pf[mi][1], bones, lacc[mi]);
        }
        #pragma unroll
        for (int nb = 0; nb < 4; ++nb) {
            bf16x8 va = lds_frag(Vsb, nb*16 + l15, quad);
            bf16x8 vc = lds_frag(Vsb, nb*16 + l15, quad + 4);
            #pragma unroll
            for (int mi = 0; mi < 2; ++mi) {
                o[mi][nb] = MFMA_BF16(pf[mi][0], va, o[mi][nb]);
                o[mi][nb] = MFMA_BF16(pf[mi][1], vc, o[mi][nb]);
            }
        }
    }

    const int b = bh >> 4, h = bh & 15;
    #pragma unroll
    for (int mi = 0; mi < 2; ++mi)
        #pragma unroll
        for (int r = 0; r < 4; ++r) {
            const int ig = rb0 + mi*16 + quad*4 + r;
            const float inv = 1.f / lacc[mi][r];
            ushort* op = Ob + ((size_t)(b * 2048 + ig)) * 1024 + h * 64 + l15;
            #pragma unroll
            for (int nb = 0; nb < 4; ++nb)
                op[nb * 16] = f2bf(o[mi][nb][r] * inv);
        }
}

// ---------------------------------------------------------------------------
extern "C" void kernel_launch(void* const* d_in, const int* in_sizes, int n_in,
                              void* d_out, int out_size, void* d_ws, size_t ws_size,
                              hipStream_t stream) {
    const float* x   = (const float*)d_in[0];
    const float* Wq  = (const float*)d_in[1];
    const float* Wkv = (const float*)d_in[2];
    const float* Wo  = (const float*)d_in[3];
    const float* bo  = (const float*)d_in[4];
    float* out = (float*)d_out;

    const size_t SEG = (size_t)8388608 * 2;   // 16 MB per bf16 [8192x1024]
    char* ws = (char*)d_ws;
    ushort* xb = (ushort*)(ws);
    ushort* Qb = (ushort*)(ws + SEG);
    ushort* Kb = (ushort*)(ws + SEG * 2);
    ushort* Vt = (ushort*)(ws + SEG * 3);     // [bh*64+d][2048]
    ushort* Ob = (ushort*)(ws + SEG * 4);
    ushort* Wt = (ushort*)(ws + SEG * 5);     // [4096][1024] bf16

    convert_x<<<dim3(4096), 256, 0, stream>>>(x, xb);
    prep_w<<<dim3(256), 256, 0, stream>>>(Wq, Wkv, Wo, Wt);
    gemm_qkv<<<dim3(8, 32), 512, 0, stream>>>(xb, Wt, Qb, Kb, Vt);
    flash_mfma<<<dim3(1024), 256, 0, stream>>>(Qb, Kb, Vt, Ob);
    gemm_out<<<dim3(4, 64), 512, 0, stream>>>(Ob, Wt + (size_t)3072 * 1024, bo, out);
}

// Round 8
// 250.853 us; speedup vs baseline: 1.0688x; 1.0104x over previous
//
#include <hip/hip_runtime.h>
#include <hip/hip_bf16.h>
#include <math.h>

typedef __attribute__((ext_vector_type(8))) short bf16x8;
typedef __attribute__((ext_vector_type(4))) float f32x4;

static __device__ inline ushort f2bf(float f) {
    union { float f; unsigned u; } v; v.f = f;
    unsigned r = (v.u + 0x7fff + ((v.u >> 16) & 1)) >> 16;   // RNE
    return (ushort)r;
}

#define GLD_LDS(g, l) \
    __builtin_amdgcn_global_load_lds( \
        (const __attribute__((address_space(1))) void*)(g), \
        (__attribute__((address_space(3))) void*)(l), 16, 0, 0)

#define MFMA_BF16(a, b, c) __builtin_amdgcn_mfma_f32_16x16x32_bf16((a), (b), (c), 0, 0, 0)

// ---------------------------------------------------------------------------
// Fused prep: blocks [0,4096) convert x fp32->bf16; blocks [4096,4352)
// transpose weights fp32 [K][N] -> Wt bf16 [4096][1024].
// ---------------------------------------------------------------------------
__global__ __launch_bounds__(256) void prep_all(
    const float* __restrict__ x, ushort* __restrict__ xb,
    const float* __restrict__ Wq, const float* __restrict__ Wkv,
    const float* __restrict__ Wo, ushort* __restrict__ Wt)
{
    if (blockIdx.x < 4096) {
        const size_t i = ((size_t)blockIdx.x * 256 + threadIdx.x) * 8;
        float4 a = *(const float4*)(x + i);
        float4 b = *(const float4*)(x + i + 4);
        bf16x8 t;
        t[0] = (short)f2bf(a.x); t[1] = (short)f2bf(a.y);
        t[2] = (short)f2bf(a.z); t[3] = (short)f2bf(a.w);
        t[4] = (short)f2bf(b.x); t[5] = (short)f2bf(b.y);
        t[6] = (short)f2bf(b.z); t[7] = (short)f2bf(b.w);
        *(bf16x8*)(xb + i) = t;
    } else {
        const int w = threadIdx.x >> 6;
        const int lane = threadIdx.x & 63;
        const int tile = (blockIdx.x - 4096) * 4 + w;
        const int r0 = (tile >> 4) << 6;
        const int k0 = (tile & 15) << 6;

        const float* src; int ld, c0;
        if (r0 < 1024)      { src = Wq;  ld = 1024; c0 = r0; }
        else if (r0 < 3072) { src = Wkv; ld = 2048; c0 = r0 - 1024; }
        else                { src = Wo;  ld = 1024; c0 = r0 - 3072; }

        ushort v[64];
        #pragma unroll
        for (int k = 0; k < 64; ++k)
            v[k] = f2bf(src[(size_t)(k0 + k) * ld + c0 + lane]);

        ushort* dst = Wt + (size_t)(r0 + lane) * 1024 + k0;
        #pragma unroll
        for (int k = 0; k < 64; k += 8) {
            bf16x8 t;
            #pragma unroll
            for (int j = 0; j < 8; ++j) t[j] = (short)v[k + j];
            *(bf16x8*)(dst + k) = t;
        }
    }
}

// ---------------------------------------------------------------------------
// gemm_qkv: R7 verbatim (measured 73.4 us, 700 TF engine, exact 256-block
// grid). 256(M)x384(N) tile, BK=32, 512 thr / 8 waves (2M x 4N), per-wave
// 128x96 = 8x6 frags. Double-buffered 80 KB LDS; stage(t+1) first; 6 B-frag
// reads; stream 8x(A-read + 6 MFMA); vmcnt(0); one barrier.
// Swizzle chunk ^= (row>>1)&3 on global source + read side (0 conflicts).
// ---------------------------------------------------------------------------
#define STG_A96(t) { ushort* d_ = As2 + ((t) & 1) * 8192 + ldst; \
    GLD_LDS(aG + (size_t)(t) * 32, d_); \
    GLD_LDS(aG + (size_t)131072 + (size_t)(t) * 32, d_ + 4096); }
#define STG_B96(t) { ushort* d_ = Bs2 + ((t) & 1) * 12288 + ldst; \
    GLD_LDS(bG + (size_t)(t) * 32, d_); \
    GLD_LDS(bG + (size_t)131072 + (size_t)(t) * 32, d_ + 4096); \
    GLD_LDS(bG + (size_t)262144 + (size_t)(t) * 32, d_ + 8192); }

__global__ __launch_bounds__(512, 2) void gemm_qkv(
    const ushort* __restrict__ A, const ushort* __restrict__ Bt,
    ushort* __restrict__ Qb, ushort* __restrict__ Kb, ushort* __restrict__ Vt)
{
    __shared__ ushort As2[2 * 8192];    // 2 x 256x32 = 32 KB
    __shared__ ushort Bs2[2 * 12288];   // 2 x 384x32 = 48 KB

    const int tid = threadIdx.x;
    const int lane = tid & 63;
    const int w = tid >> 6;
    const int l15 = lane & 15;
    const int quad = lane >> 4;
    const int wm = w >> 2, wn = w & 3;                 // 2M x 4N waves

    const int lin = blockIdx.y * 8 + blockIdx.x;       // 256 blocks, %8==0
    const int wg = (lin & 7) * 32 + (lin >> 3);        // XCD-chunked bijection
    const int rowBase = (wg >> 3) * 256;               // 32 M-tiles
    const int colBase = (wg & 7) * 384;                // 8 N-tiles

    const int sr = tid >> 2, sc = tid & 3;             // 4 thr/row
    const int ldst = sr * 32 + sc * 8;
    const int gsw = (sc ^ ((sr >> 1) & 3)) << 3;       // pre-swizzled source
    const ushort* aG = A  + (size_t)(rowBase + sr) * 1024 + gsw;
    const ushort* bG = Bt + (size_t)(colBase + sr) * 1024 + gsw;

    const int co = (quad ^ ((l15 >> 1) & 3)) << 3;

    f32x4 acc[8][6];
    #pragma unroll
    for (int i_ = 0; i_ < 8; ++i_)
        #pragma unroll
        for (int j_ = 0; j_ < 6; ++j_) acc[i_][j_] = (f32x4){0.f, 0.f, 0.f, 0.f};

    STG_A96(0) STG_B96(0)
    asm volatile("s_waitcnt vmcnt(0)" ::: "memory");
    __builtin_amdgcn_s_barrier();
    asm volatile("" ::: "memory");

    #pragma unroll 1
    for (int t = 0; t < 32; ++t) {
        const int cur = t & 1;
        if (t + 1 < 32) { STG_A96(t + 1) STG_B96(t + 1) }

        const ushort* aRd = As2 + cur * 8192  + (wm * 128 + l15) * 32;
        const ushort* bRd = Bs2 + cur * 12288 + (wn * 96 + l15) * 32;

        bf16x8 bF[6];
        #pragma unroll
        for (int ni = 0; ni < 6; ++ni)
            bF[ni] = *(const bf16x8*)(bRd + ni * 512 + co);

        __builtin_amdgcn_s_setprio(1);
        #pragma unroll
        for (int ri = 0; ri < 8; ++ri) {
            bf16x8 aF = *(const bf16x8*)(aRd + ri * 512 + co);
            #pragma unroll
            for (int ni = 0; ni < 6; ++ni)
                acc[ri][ni] = MFMA_BF16(aF, bF[ni], acc[ri][ni]);
        }
        __builtin_amdgcn_s_setprio(0);

        asm volatile("s_waitcnt vmcnt(0)" ::: "memory");
        __builtin_amdgcn_s_barrier();
        asm volatile("" ::: "memory");
    }

    // epilogue: per-frag seg routing (16-col frags never straddle)
    const float qsc = 0.18033688011112042f;   // 1/sqrt(64) * log2(e)
    #pragma unroll
    for (int ri = 0; ri < 8; ++ri) {
        #pragma unroll
        for (int ni = 0; ni < 6; ++ni) {
            const int c = colBase + wn * 96 + ni * 16 + l15;
            const int seg = c >> 10;
            const int h = (c & 1023) >> 6, d = c & 63;
            if (seg == 2) {
                const int m = rowBase + wm * 128 + ri * 16 + quad * 4;
                const int b = m >> 11, nn = m & 2047;
                ushort4 v;
                v.x = f2bf(acc[ri][ni][0]); v.y = f2bf(acc[ri][ni][1]);
                v.z = f2bf(acc[ri][ni][2]); v.w = f2bf(acc[ri][ni][3]);
                *(ushort4*)(Vt + ((size_t)(b * 16 + h) * 64 + d) * 2048 + nn) = v;
            } else {
                ushort* dst = seg ? Kb : Qb;
                const float sc2 = seg ? 1.0f : qsc;
                #pragma unroll
                for (int r = 0; r < 4; ++r) {
                    const int m = rowBase + wm * 128 + ri * 16 + quad * 4 + r;
                    const int b = m >> 11, nn = m & 2047;
                    dst[((((size_t)b * 16 + h) * 2048 + nn) << 6) + d] = f2bf(acc[ri][ni][r] * sc2);
                }
            }
        }
    }
}

// ---------------------------------------------------------------------------
// gemm_out: REVERTED to the R3 2-phase 128x256 BK=64 pipe (the version from
// the best-total round; the R4-R7 tri-buffer variant measured ~+13 us).
// 2 phases per K-tile, 16 MFMA each; stage ph A: A(u+1) [dead buf],
// ph B: B halves (u+2); boundary vmcnt(4) steady / vmcnt(0) tail.
// ---------------------------------------------------------------------------
#define STG_A(t) { ushort* d_ = &As[(t) & 1][ldst];                            \
    GLD_LDS(aS0 + (size_t)(t) * 64, d_);                                       \
    GLD_LDS(aS1 + (size_t)(t) * 64, d_ + 64 * 64); }
#define STG_B1(t) { ushort* d_ = &Bs[(t) & 1][ldst];                           \
    GLD_LDS(bS0 + (size_t)(t) * 64, d_);                                       \
    GLD_LDS(bS1 + (size_t)(t) * 64, d_ + 64 * 64); }
#define STG_B2(t) { ushort* d_ = &Bs[(t) & 1][128 * 64 + ldst];                \
    GLD_LDS(bS2 + (size_t)(t) * 64, d_);                                       \
    GLD_LDS(bS3 + (size_t)(t) * 64, d_ + 64 * 64); }

__global__ __launch_bounds__(512, 2) void gemm_out(
    const ushort* __restrict__ A, const ushort* __restrict__ Bt,
    const float* __restrict__ bo, float* __restrict__ out)
{
    __shared__ ushort As[2][128 * 64];
    __shared__ ushort Bs[2][256 * 64];
    const int tid = threadIdx.x;
    const int lane = tid & 63;
    const int w = tid >> 6;
    const int l15 = lane & 15;
    const int quad = lane >> 4;
    const int wm = w >> 2, wn = w & 3;
    const int cx = l15 & 7;
    const int lin = blockIdx.y * 4 + blockIdx.x;
    const int wg = (lin & 7) * 32 + (lin >> 3);
    const int rowBase = (wg >> 2) * 128;
    const int colBase = (wg & 3) * 256;
    const int sr = tid >> 3, sc = tid & 7;
    const int ldst = sr * 64 + sc * 8;
    const ushort* aS0 = A + (size_t)(rowBase + sr) * 1024 + ((sc ^ (sr & 7)) << 3);
    const ushort* aS1 = aS0 + (size_t)64 * 1024;
    const ushort* bS0 = Bt + (size_t)(colBase + sr) * 1024 + ((sc ^ (sr & 7)) << 3);
    const ushort* bS1 = bS0 + (size_t)64 * 1024;
    const ushort* bS2 = bS0 + (size_t)128 * 1024;
    const ushort* bS3 = bS0 + (size_t)192 * 1024;
    f32x4 acc[4][4];
    #pragma unroll
    for (int i_ = 0; i_ < 4; ++i_)
        #pragma unroll
        for (int j_ = 0; j_ < 4; ++j_) acc[i_][j_] = (f32x4){0.f, 0.f, 0.f, 0.f};
    STG_A(0) STG_B1(0) STG_B2(0) STG_B1(1) STG_B2(1)
    asm volatile("s_waitcnt vmcnt(4)" ::: "memory");
    __builtin_amdgcn_s_barrier();
    asm volatile("" ::: "memory");
    #pragma unroll 1
    for (int u = 0; u < 16; ++u) {
        const ushort* aRd = &As[u & 1][(wm * 64 + l15) * 64];
        const ushort* bRd = &Bs[u & 1][(wn * 64 + l15) * 64];
        const int c0 = (quad ^ cx) << 3, c1 = ((4 | quad) ^ cx) << 3;
        // ---- phase A: B-frags + A rows 0,1 ----
        bf16x8 bF0[4], bF1[4];
        #pragma unroll
        for (int ni = 0; ni < 4; ++ni) {
            bF0[ni] = *(const bf16x8*)(bRd + ni * 1024 + c0);
            bF1[ni] = *(const bf16x8*)(bRd + ni * 1024 + c1);
        }
        bf16x8 a00 = *(const bf16x8*)(aRd + c0);
        bf16x8 a01 = *(const bf16x8*)(aRd + c1);
        bf16x8 a10 = *(const bf16x8*)(aRd + 1024 + c0);
        bf16x8 a11 = *(const bf16x8*)(aRd + 1024 + c1);
        if (u + 1 < 16) { STG_A(u + 1) }
        __builtin_amdgcn_s_barrier();
        asm volatile("s_waitcnt lgkmcnt(0)" ::: "memory");
        __builtin_amdgcn_sched_barrier(0);
        __builtin_amdgcn_s_setprio(1);
        #pragma unroll
        for (int ni = 0; ni < 4; ++ni) {
            acc[0][ni] = MFMA_BF16(a00, bF0[ni], acc[0][ni]);
            acc[0][ni] = MFMA_BF16(a01, bF1[ni], acc[0][ni]);
        }
        #pragma unroll
        for (int ni = 0; ni < 4; ++ni) {
            acc[1][ni] = MFMA_BF16(a10, bF0[ni], acc[1][ni]);
            acc[1][ni] = MFMA_BF16(a11, bF1[ni], acc[1][ni]);
        }
        __builtin_amdgcn_s_setprio(0);
        __builtin_amdgcn_s_barrier();
        asm volatile("" ::: "memory");
        // ---- phase B: A rows 2,3 ----
        bf16x8 a20 = *(const bf16x8*)(aRd + 2 * 1024 + c0);
        bf16x8 a21 = *(const bf16x8*)(aRd + 2 * 1024 + c1);
        bf16x8 a30 = *(const bf16x8*)(aRd + 3 * 1024 + c0);
        bf16x8 a31 = *(const bf16x8*)(aRd + 3 * 1024 + c1);
        if (u + 2 < 16) { STG_B1(u + 2) STG_B2(u + 2) }
        __builtin_amdgcn_s_barrier();
        asm volatile("s_waitcnt lgkmcnt(0)" ::: "memory");
        __builtin_amdgcn_sched_barrier(0);
        __builtin_amdgcn_s_setprio(1);
        #pragma unroll
        for (int ni = 0; ni < 4; ++ni) {
            acc[2][ni] = MFMA_BF16(a20, bF0[ni], acc[2][ni]);
            acc[2][ni] = MFMA_BF16(a21, bF1[ni], acc[2][ni]);
        }
        #pragma unroll
        for (int ni = 0; ni < 4; ++ni) {
            acc[3][ni] = MFMA_BF16(a30, bF0[ni], acc[3][ni]);
            acc[3][ni] = MFMA_BF16(a31, bF1[ni], acc[3][ni]);
        }
        __builtin_amdgcn_s_setprio(0);
        if (u < 14) { asm volatile("s_waitcnt vmcnt(4)" ::: "memory"); }
        else        { asm volatile("s_waitcnt vmcnt(0)" ::: "memory"); }
        __builtin_amdgcn_s_barrier();
        asm volatile("" ::: "memory");
    }

    #pragma unroll
    for (int mi = 0; mi < 4; ++mi) {
        #pragma unroll
        for (int ni = 0; ni < 4; ++ni) {
            const int n = colBase + wn*64 + ni*16 + l15;
            const float bb = bo[n];
            #pragma unroll
            for (int r = 0; r < 4; ++r) {
                const int m = rowBase + wm*64 + mi*16 + quad*4 + r;
                out[(size_t)m * 1024 + n] = acc[mi][ni][r] + bb;
            }
        }
    }
}

// ---------------------------------------------------------------------------
// Flash attention v5: unpaired q-tiles (grid 1024, qt-descending dispatch),
// double-buffered LDS K/V, S^T trick, skip-rescale on no-new-max.
// Block = 4 waves x 32 q-rows = one 128-row q-tile.
// ---------------------------------------------------------------------------
__device__ __forceinline__ bf16x8 lds_frag(const ushort* S, int row, int chunk) {
    return *(const bf16x8*)(S + row * 64 + ((chunk ^ (row & 7)) << 3));
}

__global__ __launch_bounds__(256, 2) void flash_mfma(
    const ushort* __restrict__ Qb,
    const ushort* __restrict__ Kb,
    const ushort* __restrict__ Vt,
    ushort* __restrict__ Ob)
{
    __shared__ ushort Ks[2][4096];
    __shared__ ushort Vs[2][4096];
    __shared__ ushort PsAll[4][32][72];

    const int tid = threadIdx.x;
    const int w = tid >> 6;
    const int lane = tid & 63;
    const int l15 = lane & 15;
    const int quad = lane >> 4;
    ushort (*Ps)[72] = PsAll[w];

    const int blk = blockIdx.x;
    const int bh = ((blk & 7) << 3) | ((blk >> 3) & 7);
    const int qt = 15 - (blk >> 6);
    const int nt = 2 * qt + 2;
    const int rb0 = (qt << 7) + w * 32;

    const int sr0 = tid >> 3, sr1 = sr0 + 32;
    const int cg0 = (tid & 7) ^ (sr0 & 7);
    const int cg1 = (tid & 7) ^ (sr1 & 7);
    const ushort* kgb = Kb + (size_t)bh * 131072;
    const ushort* vgb = Vt + (size_t)bh * 131072;

    bf16x8 qf[2][2];
    #pragma unroll
    for (int mi = 0; mi < 2; ++mi) {
        const ushort* qp = Qb + ((size_t)bh * 2048 + rb0 + mi*16 + l15) * 64 + quad * 8;
        qf[mi][0] = *(const bf16x8*)qp;
        qf[mi][1] = *(const bf16x8*)(qp + 32);
    }

    bf16x8 bones;
    #pragma unroll
    for (int j = 0; j < 8; ++j) bones[j] = (short)0x3F80;   // bf16 1.0

    float m_r[2];
    f32x4 o[2][4], lacc[2];
    #pragma unroll
    for (int mi = 0; mi < 2; ++mi) {
        m_r[mi] = -INFINITY;
        lacc[mi] = (f32x4){0.f, 0.f, 0.f, 0.f};
        #pragma unroll
        for (int nb = 0; nb < 4; ++nb) o[mi][nb] = (f32x4){0.f, 0.f, 0.f, 0.f};
    }

    GLD_LDS(kgb + sr0*64 + cg0*8, &Ks[0][tid*8]);
    GLD_LDS(kgb + sr1*64 + cg1*8, &Ks[0][tid*8 + 2048]);
    GLD_LDS(vgb + (size_t)sr0*2048 + cg0*8, &Vs[0][tid*8]);
    GLD_LDS(vgb + (size_t)sr1*2048 + cg1*8, &Vs[0][tid*8 + 2048]);

    for (int t = 0; t < nt; ++t) {
        __syncthreads();
        const int cur = t & 1;
        if (t + 1 < nt) {
            const int jn = t + 1;
            ushort* kd = &Ks[cur ^ 1][tid * 8];
            ushort* vd = &Vs[cur ^ 1][tid * 8];
            GLD_LDS(kgb + (size_t)jn*4096 + sr0*64 + cg0*8, kd);
            GLD_LDS(kgb + (size_t)jn*4096 + sr1*64 + cg1*8, kd + 2048);
            GLD_LDS(vgb + (size_t)sr0*2048 + jn*64 + cg0*8, vd);
            GLD_LDS(vgb + (size_t)sr1*2048 + jn*64 + cg1*8, vd + 2048);
        }
        const int j0 = t << 6;
        if (j0 > rb0 + 31) continue;

        const ushort* Ksb = Ks[cur];
        const ushort* Vsb = Vs[cur];

        f32x4 St[2][4];
        #pragma unroll
        for (int kb = 0; kb < 4; ++kb) {
            bf16x8 ka = lds_frag(Ksb, kb*16 + l15, quad);
            bf16x8 kc = lds_frag(Ksb, kb*16 + l15, quad + 4);
            #pragma unroll
            for (int mi = 0; mi < 2; ++mi) {
                f32x4 s = (f32x4){0.f, 0.f, 0.f, 0.f};
                s = MFMA_BF16(ka, qf[mi][0], s);
                s = MFMA_BF16(kc, qf[mi][1], s);
                St[mi][kb] = s;
            }
        }

        #pragma unroll
        for (int mi = 0; mi < 2; ++mi) {
            const int qrow = rb0 + mi*16 + l15;
            if (j0 + 63 > rb0 + mi*16) {
                #pragma unroll
                for (int kb = 0; kb < 4; ++kb) {
                    const int kbase = j0 + kb*16 + quad*4;
                    #pragma unroll
                    for (int r = 0; r < 4; ++r)
                        if (kbase + r > qrow) St[mi][kb][r] = -INFINITY;
                }
            }
            f32x4 mv = St[mi][0];
            #pragma unroll
            for (int kb = 1; kb < 4; ++kb)
                #pragma unroll
                for (int r = 0; r < 4; ++r) mv[r] = fmaxf(mv[r], St[mi][kb][r]);
            float mx = fmaxf(fmaxf(mv[0], mv[1]), fmaxf(mv[2], mv[3]));
            mx = fmaxf(mx, __shfl_xor(mx, 16));
            mx = fmaxf(mx, __shfl_xor(mx, 32));
            const float mold = m_r[mi];
            const float mnew = fmaxf(mold, mx);
            if (__any(mnew > mold)) {
                m_r[mi] = mnew;
                const float corr = __builtin_amdgcn_exp2f(mold - mnew);
                float ct[4];
                #pragma unroll
                for (int r = 0; r < 4; ++r) ct[r] = __shfl(corr, quad*4 + r);
                #pragma unroll
                for (int r = 0; r < 4; ++r) lacc[mi][r] *= ct[r];
                #pragma unroll
                for (int nb = 0; nb < 4; ++nb)
                    #pragma unroll
                    for (int r = 0; r < 4; ++r) o[mi][nb][r] *= ct[r];
            }
            #pragma unroll
            for (int kb = 0; kb < 4; ++kb)
                #pragma unroll
                for (int r = 0; r < 4; ++r)
                    St[mi][kb][r] = __builtin_amdgcn_exp2f(St[mi][kb][r] - mnew);
            #pragma unroll
            for (int kb = 0; kb < 4; ++kb) {
                union { float f; unsigned u; } c0_, c1_, c2_, c3_;
                c0_.f = St[mi][kb][0]; c1_.f = St[mi][kb][1];
                c2_.f = St[mi][kb][2]; c3_.f = St[mi][kb][3];
                uint2 pk;
                pk.x = (c0_.u >> 16) | (c1_.u & 0xFFFF0000u);
                pk.y = (c2_.u >> 16) | (c3_.u & 0xFFFF0000u);
                *(uint2*)&Ps[mi*16 + l15][kb*16 + quad*4] = pk;
            }
        }

        bf16x8 pf[2][2];
        #pragma unroll
        for (int mi = 0; mi < 2; ++mi) {
            pf[mi][0] = *(const bf16x8*)&Ps[mi*16 + l15][quad * 8];
            pf[mi][1] = *(const bf16x8*)&Ps[mi*16 + l15][32 + quad * 8];
        }
        #pragma unroll
        for (int mi = 0; mi < 2; ++mi) {
            lacc[mi] = MFMA_BF16(pf[mi][0], bones, lacc[mi]);
            lacc[mi] = MFMA_BF16(pf[mi][1], bones, lacc[mi]);
        }
        #pragma unroll
        for (int nb = 0; nb < 4; ++nb) {
            bf16x8 va = lds_frag(Vsb, nb*16 + l15, quad);
            bf16x8 vc = lds_frag(Vsb, nb*16 + l15, quad + 4);
            #pragma unroll
            for (int mi = 0; mi < 2; ++mi) {
                o[mi][nb] = MFMA_BF16(pf[mi][0], va, o[mi][nb]);
                o[mi][nb] = MFMA_BF16(pf[mi][1], vc, o[mi][nb]);
            }
        }
    }

    const int b = bh >> 4, h = bh & 15;
    #pragma unroll
    for (int mi = 0; mi < 2; ++mi)
        #pragma unroll
        for (int r = 0; r < 4; ++r) {
            const int ig = rb0 + mi*16 + quad*4 + r;
            const float inv = 1.f / lacc[mi][r];
            ushort* op = Ob + ((size_t)(b * 2048 + ig)) * 1024 + h * 64 + l15;
            #pragma unroll
            for (int nb = 0; nb < 4; ++nb)
                op[nb * 16] = f2bf(o[mi][nb][r] * inv);
        }
}

// ---------------------------------------------------------------------------
extern "C" void kernel_launch(void* const* d_in, const int* in_sizes, int n_in,
                              void* d_out, int out_size, void* d_ws, size_t ws_size,
                              hipStream_t stream) {
    const float* x   = (const float*)d_in[0];
    const float* Wq  = (const float*)d_in[1];
    const float* Wkv = (const float*)d_in[2];
    const float* Wo  = (const float*)d_in[3];
    const float* bo  = (const float*)d_in[4];
    float* out = (float*)d_out;

    const size_t SEG = (size_t)8388608 * 2;   // 16 MB per bf16 [8192x1024]
    char* ws = (char*)d_ws;
    ushort* xb = (ushort*)(ws);
    ushort* Qb = (ushort*)(ws + SEG);
    ushort* Kb = (ushort*)(ws + SEG * 2);
    ushort* Vt = (ushort*)(ws + SEG * 3);     // [bh*64+d][2048]
    ushort* Ob = (ushort*)(ws + SEG * 4);
    ushort* Wt = (ushort*)(ws + SEG * 5);     // [4096][1024] bf16

    prep_all<<<dim3(4352), 256, 0, stream>>>(x, xb, Wq, Wkv, Wo, Wt);
    gemm_qkv<<<dim3(8, 32), 512, 0, stream>>>(xb, Wt, Qb, Kb, Vt);
    flash_mfma<<<dim3(1024), 256, 0, stream>>>(Qb, Kb, Vt, Ob);
    gemm_out<<<dim3(4, 64), 512, 0, stream>>>(Ob, Wt + (size_t)3072 * 1024, bo, out);
}

// Round 9
// 249.448 us; speedup vs baseline: 1.0749x; 1.0056x over previous
//
#include <hip/hip_runtime.h>
#include <hip/hip_bf16.h>
#include <math.h>

typedef __attribute__((ext_vector_type(8))) short bf16x8;
typedef __attribute__((ext_vector_type(4))) float f32x4;

static __device__ inline ushort f2bf(float f) {
    union { float f; unsigned u; } v; v.f = f;
    unsigned r = (v.u + 0x7fff + ((v.u >> 16) & 1)) >> 16;   // RNE
    return (ushort)r;
}

#define GLD_LDS(g, l) \
    __builtin_amdgcn_global_load_lds( \
        (const __attribute__((address_space(1))) void*)(g), \
        (__attribute__((address_space(3))) void*)(l), 16, 0, 0)

#define MFMA_BF16(a, b, c) __builtin_amdgcn_mfma_f32_16x16x32_bf16((a), (b), (c), 0, 0, 0)

// ---------------------------------------------------------------------------
// Fused prep: blocks [0,4096) convert x fp32->bf16; blocks [4096,4352)
// transpose weights fp32 [K][N] -> Wt bf16 [4096][1024].
// ---------------------------------------------------------------------------
__global__ __launch_bounds__(256) void prep_all(
    const float* __restrict__ x, ushort* __restrict__ xb,
    const float* __restrict__ Wq, const float* __restrict__ Wkv,
    const float* __restrict__ Wo, ushort* __restrict__ Wt)
{
    if (blockIdx.x < 4096) {
        const size_t i = ((size_t)blockIdx.x * 256 + threadIdx.x) * 8;
        float4 a = *(const float4*)(x + i);
        float4 b = *(const float4*)(x + i + 4);
        bf16x8 t;
        t[0] = (short)f2bf(a.x); t[1] = (short)f2bf(a.y);
        t[2] = (short)f2bf(a.z); t[3] = (short)f2bf(a.w);
        t[4] = (short)f2bf(b.x); t[5] = (short)f2bf(b.y);
        t[6] = (short)f2bf(b.z); t[7] = (short)f2bf(b.w);
        *(bf16x8*)(xb + i) = t;
    } else {
        const int w = threadIdx.x >> 6;
        const int lane = threadIdx.x & 63;
        const int tile = (blockIdx.x - 4096) * 4 + w;
        const int r0 = (tile >> 4) << 6;
        const int k0 = (tile & 15) << 6;

        const float* src; int ld, c0;
        if (r0 < 1024)      { src = Wq;  ld = 1024; c0 = r0; }
        else if (r0 < 3072) { src = Wkv; ld = 2048; c0 = r0 - 1024; }
        else                { src = Wo;  ld = 1024; c0 = r0 - 3072; }

        ushort v[64];
        #pragma unroll
        for (int k = 0; k < 64; ++k)
            v[k] = f2bf(src[(size_t)(k0 + k) * ld + c0 + lane]);

        ushort* dst = Wt + (size_t)(r0 + lane) * 1024 + k0;
        #pragma unroll
        for (int k = 0; k < 64; k += 8) {
            bf16x8 t;
            #pragma unroll
            for (int j = 0; j < 8; ++j) t[j] = (short)v[k + j];
            *(bf16x8*)(dst + k) = t;
        }
    }
}

// ---------------------------------------------------------------------------
// R3-proven 2-phase 128x256 BK=64 GEMM pipe (best-total config, 245.8 us).
// 2 phases per K-tile, 16 MFMA each; stage ph A: A(u+1) [dead buf],
// ph B: B halves (u+2) [live buf, B fully consumed in ph A, barrier-sep].
// Boundary vmcnt(4) steady / vmcnt(0) tail. Swizzle chunk ^= row&7 on
// GLOBAL source + read side (0 conflicts, verified R2-R4).
// 256-col tiles align 4 heads/block -> clean 128-B Q/K row writes
// (WRITE_SIZE 49 MB ~= ideal; R7's 384-tile cost +20 MB amplification).
// ---------------------------------------------------------------------------
#define STG_A(t) { ushort* d_ = &As[(t) & 1][ldst];                            \
    GLD_LDS(aS0 + (size_t)(t) * 64, d_);                                       \
    GLD_LDS(aS1 + (size_t)(t) * 64, d_ + 64 * 64); }
#define STG_B1(t) { ushort* d_ = &Bs[(t) & 1][ldst];                           \
    GLD_LDS(bS0 + (size_t)(t) * 64, d_);                                       \
    GLD_LDS(bS1 + (size_t)(t) * 64, d_ + 64 * 64); }
#define STG_B2(t) { ushort* d_ = &Bs[(t) & 1][128 * 64 + ldst];                \
    GLD_LDS(bS2 + (size_t)(t) * 64, d_);                                       \
    GLD_LDS(bS3 + (size_t)(t) * 64, d_ + 64 * 64); }

#define GEMM_PIPE(Aptr, Btptr, NXT, NWG)                                       \
    __shared__ ushort As[2][128 * 64];                                         \
    __shared__ ushort Bs[2][256 * 64];                                         \
    const int tid = threadIdx.x;                                               \
    const int lane = tid & 63;                                                 \
    const int w = tid >> 6;                                                    \
    const int l15 = lane & 15;                                                 \
    const int quad = lane >> 4;                                                \
    const int wm = w >> 2, wn = w & 3;                                         \
    const int cx = l15 & 7;                                                    \
    const int lin = blockIdx.y * (NXT) + blockIdx.x;                           \
    const int wg = (lin & 7) * ((NWG) >> 3) + (lin >> 3);                      \
    const int rowBase = (wg / (NXT)) * 128;                                    \
    const int colBase = (wg % (NXT)) * 256;                                    \
    const int sr = tid >> 3, sc = tid & 7;                                     \
    const int ldst = sr * 64 + sc * 8;                                         \
    const ushort* aS0 = (Aptr) + (size_t)(rowBase + sr) * 1024 + ((sc ^ (sr & 7)) << 3); \
    const ushort* aS1 = aS0 + (size_t)64 * 1024;                               \
    const ushort* bS0 = (Btptr) + (size_t)(colBase + sr) * 1024 + ((sc ^ (sr & 7)) << 3); \
    const ushort* bS1 = bS0 + (size_t)64 * 1024;                               \
    const ushort* bS2 = bS0 + (size_t)128 * 1024;                              \
    const ushort* bS3 = bS0 + (size_t)192 * 1024;                              \
    f32x4 acc[4][4];                                                           \
    _Pragma("unroll")                                                          \
    for (int i_ = 0; i_ < 4; ++i_)                                             \
        _Pragma("unroll")                                                      \
        for (int j_ = 0; j_ < 4; ++j_) acc[i_][j_] = (f32x4){0.f, 0.f, 0.f, 0.f}; \
    STG_A(0) STG_B1(0) STG_B2(0) STG_B1(1) STG_B2(1)                           \
    asm volatile("s_waitcnt vmcnt(4)" ::: "memory");                           \
    __builtin_amdgcn_s_barrier();                                              \
    asm volatile("" ::: "memory");                                             \
    _Pragma("unroll 1")                                                        \
    for (int u = 0; u < 16; ++u) {                                             \
        const ushort* aRd = &As[u & 1][(wm * 64 + l15) * 64];                  \
        const ushort* bRd = &Bs[u & 1][(wn * 64 + l15) * 64];                  \
        const int c0 = (quad ^ cx) << 3, c1 = ((4 | quad) ^ cx) << 3;          \
        bf16x8 bF0[4], bF1[4];                                                 \
        _Pragma("unroll")                                                      \
        for (int ni = 0; ni < 4; ++ni) {                                       \
            bF0[ni] = *(const bf16x8*)(bRd + ni * 1024 + c0);                  \
            bF1[ni] = *(const bf16x8*)(bRd + ni * 1024 + c1);                  \
        }                                                                      \
        bf16x8 a00 = *(const bf16x8*)(aRd + c0);                               \
        bf16x8 a01 = *(const bf16x8*)(aRd + c1);                               \
        bf16x8 a10 = *(const bf16x8*)(aRd + 1024 + c0);                        \
        bf16x8 a11 = *(const bf16x8*)(aRd + 1024 + c1);                        \
        if (u + 1 < 16) { STG_A(u + 1) }                                       \
        __builtin_amdgcn_s_barrier();                                          \
        asm volatile("s_waitcnt lgkmcnt(0)" ::: "memory");                     \
        __builtin_amdgcn_sched_barrier(0);                                     \
        __builtin_amdgcn_s_setprio(1);                                         \
        _Pragma("unroll")                                                      \
        for (int ni = 0; ni < 4; ++ni) {                                       \
            acc[0][ni] = MFMA_BF16(a00, bF0[ni], acc[0][ni]);                  \
            acc[0][ni] = MFMA_BF16(a01, bF1[ni], acc[0][ni]);                  \
        }                                                                      \
        _Pragma("unroll")                                                      \
        for (int ni = 0; ni < 4; ++ni) {                                       \
            acc[1][ni] = MFMA_BF16(a10, bF0[ni], acc[1][ni]);                  \
            acc[1][ni] = MFMA_BF16(a11, bF1[ni], acc[1][ni]);                  \
        }                                                                      \
        __builtin_amdgcn_s_setprio(0);                                         \
        __builtin_amdgcn_s_barrier();                                          \
        asm volatile("" ::: "memory");                                         \
        bf16x8 a20 = *(const bf16x8*)(aRd + 2 * 1024 + c0);                    \
        bf16x8 a21 = *(const bf16x8*)(aRd + 2 * 1024 + c1);                    \
        bf16x8 a30 = *(const bf16x8*)(aRd + 3 * 1024 + c0);                    \
        bf16x8 a31 = *(const bf16x8*)(aRd + 3 * 1024 + c1);                    \
        if (u + 2 < 16) { STG_B1(u + 2) STG_B2(u + 2) }                        \
        __builtin_amdgcn_s_barrier();                                          \
        asm volatile("s_waitcnt lgkmcnt(0)" ::: "memory");                     \
        __builtin_amdgcn_sched_barrier(0);                                     \
        __builtin_amdgcn_s_setprio(1);                                         \
        _Pragma("unroll")                                                      \
        for (int ni = 0; ni < 4; ++ni) {                                       \
            acc[2][ni] = MFMA_BF16(a20, bF0[ni], acc[2][ni]);                  \
            acc[2][ni] = MFMA_BF16(a21, bF1[ni], acc[2][ni]);                  \
        }                                                                      \
        _Pragma("unroll")                                                      \
        for (int ni = 0; ni < 4; ++ni) {                                       \
            acc[3][ni] = MFMA_BF16(a30, bF0[ni], acc[3][ni]);                  \
            acc[3][ni] = MFMA_BF16(a31, bF1[ni], acc[3][ni]);                  \
        }                                                                      \
        __builtin_amdgcn_s_setprio(0);                                         \
        if (u < 14) { asm volatile("s_waitcnt vmcnt(4)" ::: "memory"); }       \
        else        { asm volatile("s_waitcnt vmcnt(0)" ::: "memory"); }       \
        __builtin_amdgcn_s_barrier();                                          \
        asm volatile("" ::: "memory");                                         \
    }

// ---------------------------------------------------------------------------
// GEMM 1: xb x Wt[0:3072] -> Q (pre-scaled by 0.125*log2e), K in [bh][n][64];
//         V directly transposed into Vt [bh*64+d][2048]
// ---------------------------------------------------------------------------
__global__ __launch_bounds__(512, 2) void gemm_qkv(
    const ushort* __restrict__ A, const ushort* __restrict__ Bt,
    ushort* __restrict__ Qb, ushort* __restrict__ Kb, ushort* __restrict__ Vt)
{
    GEMM_PIPE(A, Bt, 12, 768)

    const int seg = colBase >> 10;          // 0=Q 1=K 2=V
    if (seg == 2) {
        #pragma unroll
        for (int mi = 0; mi < 4; ++mi) {
            #pragma unroll
            for (int ni = 0; ni < 4; ++ni) {
                const int c = (colBase + wn*64 + ni*16 + l15) & 1023;
                const int h = c >> 6, d = c & 63;
                const int m = rowBase + wm*64 + mi*16 + quad*4;
                const int b = m >> 11, nn = m & 2047;
                ushort4 v;
                v.x = f2bf(acc[mi][ni][0]); v.y = f2bf(acc[mi][ni][1]);
                v.z = f2bf(acc[mi][ni][2]); v.w = f2bf(acc[mi][ni][3]);
                *(ushort4*)(Vt + ((size_t)(b*16 + h)*64 + d)*2048 + nn) = v;
            }
        }
    } else {
        ushort* dst = seg ? Kb : Qb;
        // Q pre-scale: 1/sqrt(64) * log2(e)  (softmax runs in base-2 domain)
        const float sc2 = seg ? 1.0f : 0.18033688011112042f;
        #pragma unroll
        for (int mi = 0; mi < 4; ++mi) {
            #pragma unroll
            for (int ni = 0; ni < 4; ++ni) {
                const int c = (colBase + wn*64 + ni*16 + l15) & 1023;
                const int h = c >> 6, d = c & 63;
                #pragma unroll
                for (int r = 0; r < 4; ++r) {
                    const int m = rowBase + wm*64 + mi*16 + quad*4 + r;
                    const int b = m >> 11, nn = m & 2047;
                    dst[((((size_t)b*16 + h)*2048 + nn) << 6) + d] = f2bf(acc[mi][ni][r] * sc2);
                }
            }
        }
    }
}

// ---------------------------------------------------------------------------
// GEMM 2: Ob x Wt[3072:4096] + bo -> fp32 out
// ---------------------------------------------------------------------------
__global__ __launch_bounds__(512, 2) void gemm_out(
    const ushort* __restrict__ A, const ushort* __restrict__ Bt,
    const float* __restrict__ bo, float* __restrict__ out)
{
    GEMM_PIPE(A, Bt, 4, 256)

    #pragma unroll
    for (int mi = 0; mi < 4; ++mi) {
        #pragma unroll
        for (int ni = 0; ni < 4; ++ni) {
            const int n = colBase + wn*64 + ni*16 + l15;
            const float bb = bo[n];
            #pragma unroll
            for (int r = 0; r < 4; ++r) {
                const int m = rowBase + wm*64 + mi*16 + quad*4 + r;
                out[(size_t)m * 1024 + n] = acc[mi][ni][r] + bb;
            }
        }
    }
}

// ---------------------------------------------------------------------------
// Flash attention v5: unpaired q-tiles (grid 1024, qt-descending dispatch),
// double-buffered LDS K/V, S^T trick, skip-rescale on no-new-max.
// Block = 4 waves x 32 q-rows = one 128-row q-tile.
// ---------------------------------------------------------------------------
__device__ __forceinline__ bf16x8 lds_frag(const ushort* S, int row, int chunk) {
    return *(const bf16x8*)(S + row * 64 + ((chunk ^ (row & 7)) << 3));
}

__global__ __launch_bounds__(256, 2) void flash_mfma(
    const ushort* __restrict__ Qb,
    const ushort* __restrict__ Kb,
    const ushort* __restrict__ Vt,
    ushort* __restrict__ Ob)
{
    __shared__ ushort Ks[2][4096];
    __shared__ ushort Vs[2][4096];
    __shared__ ushort PsAll[4][32][72];

    const int tid = threadIdx.x;
    const int w = tid >> 6;
    const int lane = tid & 63;
    const int l15 = lane & 15;
    const int quad = lane >> 4;
    ushort (*Ps)[72] = PsAll[w];

    const int blk = blockIdx.x;
    const int bh = ((blk & 7) << 3) | ((blk >> 3) & 7);
    const int qt = 15 - (blk >> 6);
    const int nt = 2 * qt + 2;
    const int rb0 = (qt << 7) + w * 32;

    const int sr0 = tid >> 3, sr1 = sr0 + 32;
    const int cg0 = (tid & 7) ^ (sr0 & 7);
    const int cg1 = (tid & 7) ^ (sr1 & 7);
    const ushort* kgb = Kb + (size_t)bh * 131072;
    const ushort* vgb = Vt + (size_t)bh * 131072;

    bf16x8 qf[2][2];
    #pragma unroll
    for (int mi = 0; mi < 2; ++mi) {
        const ushort* qp = Qb + ((size_t)bh * 2048 + rb0 + mi*16 + l15) * 64 + quad * 8;
        qf[mi][0] = *(const bf16x8*)qp;
        qf[mi][1] = *(const bf16x8*)(qp + 32);
    }

    bf16x8 bones;
    #pragma unroll
    for (int j = 0; j < 8; ++j) bones[j] = (short)0x3F80;   // bf16 1.0

    float m_r[2];
    f32x4 o[2][4], lacc[2];
    #pragma unroll
    for (int mi = 0; mi < 2; ++mi) {
        m_r[mi] = -INFINITY;
        lacc[mi] = (f32x4){0.f, 0.f, 0.f, 0.f};
        #pragma unroll
        for (int nb = 0; nb < 4; ++nb) o[mi][nb] = (f32x4){0.f, 0.f, 0.f, 0.f};
    }

    GLD_LDS(kgb + sr0*64 + cg0*8, &Ks[0][tid*8]);
    GLD_LDS(kgb + sr1*64 + cg1*8, &Ks[0][tid*8 + 2048]);
    GLD_LDS(vgb + (size_t)sr0*2048 + cg0*8, &Vs[0][tid*8]);
    GLD_LDS(vgb + (size_t)sr1*2048 + cg1*8, &Vs[0][tid*8 + 2048]);

    for (int t = 0; t < nt; ++t) {
        __syncthreads();
        const int cur = t & 1;
        if (t + 1 < nt) {
            const int jn = t + 1;
            ushort* kd = &Ks[cur ^ 1][tid * 8];
            ushort* vd = &Vs[cur ^ 1][tid * 8];
            GLD_LDS(kgb + (size_t)jn*4096 + sr0*64 + cg0*8, kd);
            GLD_LDS(kgb + (size_t)jn*4096 + sr1*64 + cg1*8, kd + 2048);
            GLD_LDS(vgb + (size_t)sr0*2048 + jn*64 + cg0*8, vd);
            GLD_LDS(vgb + (size_t)sr1*2048 + jn*64 + cg1*8, vd + 2048);
        }
        const int j0 = t << 6;
        if (j0 > rb0 + 31) continue;

        const ushort* Ksb = Ks[cur];
        const ushort* Vsb = Vs[cur];

        f32x4 St[2][4];
        #pragma unroll
        for (int kb = 0; kb < 4; ++kb) {
            bf16x8 ka = lds_frag(Ksb, kb*16 + l15, quad);
            bf16x8 kc = lds_frag(Ksb, kb*16 + l15, quad + 4);
            #pragma unroll
            for (int mi = 0; mi < 2; ++mi) {
                f32x4 s = (f32x4){0.f, 0.f, 0.f, 0.f};
                s = MFMA_BF16(ka, qf[mi][0], s);
                s = MFMA_BF16(kc, qf[mi][1], s);
                St[mi][kb] = s;
            }
        }

        #pragma unroll
        for (int mi = 0; mi < 2; ++mi) {
            const int qrow = rb0 + mi*16 + l15;
            if (j0 + 63 > rb0 + mi*16) {
                #pragma unroll
                for (int kb = 0; kb < 4; ++kb) {
                    const int kbase = j0 + kb*16 + quad*4;
                    #pragma unroll
                    for (int r = 0; r < 4; ++r)
                        if (kbase + r > qrow) St[mi][kb][r] = -INFINITY;
                }
            }
            f32x4 mv = St[mi][0];
            #pragma unroll
            for (int kb = 1; kb < 4; ++kb)
                #pragma unroll
                for (int r = 0; r < 4; ++r) mv[r] = fmaxf(mv[r], St[mi][kb][r]);
            float mx = fmaxf(fmaxf(mv[0], mv[1]), fmaxf(mv[2], mv[3]));
            mx = fmaxf(mx, __shfl_xor(mx, 16));
            mx = fmaxf(mx, __shfl_xor(mx, 32));
            const float mold = m_r[mi];
            const float mnew = fmaxf(mold, mx);
            if (__any(mnew > mold)) {
                m_r[mi] = mnew;
                const float corr = __builtin_amdgcn_exp2f(mold - mnew);
                float ct[4];
                #pragma unroll
                for (int r = 0; r < 4; ++r) ct[r] = __shfl(corr, quad*4 + r);
                #pragma unroll
                for (int r = 0; r < 4; ++r) lacc[mi][r] *= ct[r];
                #pragma unroll
                for (int nb = 0; nb < 4; ++nb)
                    #pragma unroll
                    for (int r = 0; r < 4; ++r) o[mi][nb][r] *= ct[r];
            }
            #pragma unroll
            for (int kb = 0; kb < 4; ++kb)
                #pragma unroll
                for (int r = 0; r < 4; ++r)
                    St[mi][kb][r] = __builtin_amdgcn_exp2f(St[mi][kb][r] - mnew);
            #pragma unroll
            for (int kb = 0; kb < 4; ++kb) {
                union { float f; unsigned u; } c0_, c1_, c2_, c3_;
                c0_.f = St[mi][kb][0]; c1_.f = St[mi][kb][1];
                c2_.f = St[mi][kb][2]; c3_.f = St[mi][kb][3];
                uint2 pk;
                pk.x = (c0_.u >> 16) | (c1_.u & 0xFFFF0000u);
                pk.y = (c2_.u >> 16) | (c3_.u & 0xFFFF0000u);
                *(uint2*)&Ps[mi*16 + l15][kb*16 + quad*4] = pk;
            }
        }

        bf16x8 pf[2][2];
        #pragma unroll
        for (int mi = 0; mi < 2; ++mi) {
            pf[mi][0] = *(const bf16x8*)&Ps[mi*16 + l15][quad * 8];
            pf[mi][1] = *(const bf16x8*)&Ps[mi*16 + l15][32 + quad * 8];
        }
        #pragma unroll
        for (int mi = 0; mi < 2; ++mi) {
            lacc[mi] = MFMA_BF16(pf[mi][0], bones, lacc[mi]);
            lacc[mi] = MFMA_BF16(pf[mi][1], bones, lacc[mi]);
        }
        #pragma unroll
        for (int nb = 0; nb < 4; ++nb) {
            bf16x8 va = lds_frag(Vsb, nb*16 + l15, quad);
            bf16x8 vc = lds_frag(Vsb, nb*16 + l15, quad + 4);
            #pragma unroll
            for (int mi = 0; mi < 2; ++mi) {
                o[mi][nb] = MFMA_BF16(pf[mi][0], va, o[mi][nb]);
                o[mi][nb] = MFMA_BF16(pf[mi][1], vc, o[mi][nb]);
            }
        }
    }

    const int b = bh >> 4, h = bh & 15;
    #pragma unroll
    for (int mi = 0; mi < 2; ++mi)
        #pragma unroll
        for (int r = 0; r < 4; ++r) {
            const int ig = rb0 + mi*16 + quad*4 + r;
            const float inv = 1.f / lacc[mi][r];
            ushort* op = Ob + ((size_t)(b * 2048 + ig)) * 1024 + h * 64 + l15;
            #pragma unroll
            for (int nb = 0; nb < 4; ++nb)
                op[nb * 16] = f2bf(o[mi][nb][r] * inv);
        }
}

// ---------------------------------------------------------------------------
extern "C" void kernel_launch(void* const* d_in, const int* in_sizes, int n_in,
                              void* d_out, int out_size, void* d_ws, size_t ws_size,
                              hipStream_t stream) {
    const float* x   = (const float*)d_in[0];
    const float* Wq  = (const float*)d_in[1];
    const float* Wkv = (const float*)d_in[2];
    const float* Wo  = (const float*)d_in[3];
    const float* bo  = (const float*)d_in[4];
    float* out = (float*)d_out;

    const size_t SEG = (size_t)8388608 * 2;   // 16 MB per bf16 [8192x1024]
    char* ws = (char*)d_ws;
    ushort* xb = (ushort*)(ws);
    ushort* Qb = (ushort*)(ws + SEG);
    ushort* Kb = (ushort*)(ws + SEG * 2);
    ushort* Vt = (ushort*)(ws + SEG * 3);     // [bh*64+d][2048]
    ushort* Ob = (ushort*)(ws + SEG * 4);
    ushort* Wt = (ushort*)(ws + SEG * 5);     // [4096][1024] bf16

    prep_all<<<dim3(4352), 256, 0, stream>>>(x, xb, Wq, Wkv, Wo, Wt);
    gemm_qkv<<<dim3(12, 64), 512, 0, stream>>>(xb, Wt, Qb, Kb, Vt);
    flash_mfma<<<dim3(1024), 256, 0, stream>>>(Qb, Kb, Vt, Ob);
    gemm_out<<<dim3(4, 64), 512, 0, stream>>>(Ob, Wt + (size_t)3072 * 1024, bo, out);
}

// Round 10
// 246.819 us; speedup vs baseline: 1.0863x; 1.0107x over previous
//
#include <hip/hip_runtime.h>
#include <hip/hip_bf16.h>
#include <math.h>

typedef __attribute__((ext_vector_type(8))) short bf16x8;
typedef __attribute__((ext_vector_type(4))) float f32x4;

static __device__ inline ushort f2bf(float f) {
    union { float f; unsigned u; } v; v.f = f;
    unsigned r = (v.u + 0x7fff + ((v.u >> 16) & 1)) >> 16;   // RNE
    return (ushort)r;
}

#define GLD_LDS(g, l) \
    __builtin_amdgcn_global_load_lds( \
        (const __attribute__((address_space(1))) void*)(g), \
        (__attribute__((address_space(3))) void*)(l), 16, 0, 0)

#define MFMA_BF16(a, b, c) __builtin_amdgcn_mfma_f32_16x16x32_bf16((a), (b), (c), 0, 0, 0)

// ---------------------------------------------------------------------------
// Fused prep: blocks [0,4096) convert x fp32->bf16; blocks [4096,4352)
// transpose weights fp32 [K][N] -> Wt bf16 [4096][1024].
// ---------------------------------------------------------------------------
__global__ __launch_bounds__(256) void prep_all(
    const float* __restrict__ x, ushort* __restrict__ xb,
    const float* __restrict__ Wq, const float* __restrict__ Wkv,
    const float* __restrict__ Wo, ushort* __restrict__ Wt)
{
    if (blockIdx.x < 4096) {
        const size_t i = ((size_t)blockIdx.x * 256 + threadIdx.x) * 8;
        float4 a = *(const float4*)(x + i);
        float4 b = *(const float4*)(x + i + 4);
        bf16x8 t;
        t[0] = (short)f2bf(a.x); t[1] = (short)f2bf(a.y);
        t[2] = (short)f2bf(a.z); t[3] = (short)f2bf(a.w);
        t[4] = (short)f2bf(b.x); t[5] = (short)f2bf(b.y);
        t[6] = (short)f2bf(b.z); t[7] = (short)f2bf(b.w);
        *(bf16x8*)(xb + i) = t;
    } else {
        const int w = threadIdx.x >> 6;
        const int lane = threadIdx.x & 63;
        const int tile = (blockIdx.x - 4096) * 4 + w;
        const int r0 = (tile >> 4) << 6;
        const int k0 = (tile & 15) << 6;

        const float* src; int ld, c0;
        if (r0 < 1024)      { src = Wq;  ld = 1024; c0 = r0; }
        else if (r0 < 3072) { src = Wkv; ld = 2048; c0 = r0 - 1024; }
        else                { src = Wo;  ld = 1024; c0 = r0 - 3072; }

        ushort v[64];
        #pragma unroll
        for (int k = 0; k < 64; ++k)
            v[k] = f2bf(src[(size_t)(k0 + k) * ld + c0 + lane]);

        ushort* dst = Wt + (size_t)(r0 + lane) * 1024 + k0;
        #pragma unroll
        for (int k = 0; k < 64; k += 8) {
            bf16x8 t;
            #pragma unroll
            for (int j = 0; j < 8; ++j) t[j] = (short)v[k + j];
            *(bf16x8*)(dst + k) = t;
        }
    }
}

// ---------------------------------------------------------------------------
// 2-phase 128x256 BK=64 GEMM pipe (session-converged best config).
// 2 phases per K-tile, 16 MFMA each; stage ph A: A(u+1) [dead buf],
// ph B: B halves (u+2) [live buf, B fully consumed in ph A, barrier-sep].
// Boundary vmcnt(4) steady / vmcnt(0) tail. Swizzle chunk ^= row&7 on
// GLOBAL source + read side (0 conflicts measured). 256-col tiles align
// 4 heads/block -> clean 128-B Q/K row writes (WRITE_SIZE ~= 49 MB ideal).
// ---------------------------------------------------------------------------
#define STG_A(t) { ushort* d_ = &As[(t) & 1][ldst];                            \
    GLD_LDS(aS0 + (size_t)(t) * 64, d_);                                       \
    GLD_LDS(aS1 + (size_t)(t) * 64, d_ + 64 * 64); }
#define STG_B1(t) { ushort* d_ = &Bs[(t) & 1][ldst];                           \
    GLD_LDS(bS0 + (size_t)(t) * 64, d_);                                       \
    GLD_LDS(bS1 + (size_t)(t) * 64, d_ + 64 * 64); }
#define STG_B2(t) { ushort* d_ = &Bs[(t) & 1][128 * 64 + ldst];                \
    GLD_LDS(bS2 + (size_t)(t) * 64, d_);                                       \
    GLD_LDS(bS3 + (size_t)(t) * 64, d_ + 64 * 64); }

#define GEMM_PIPE(Aptr, Btptr, NXT, NWG)                                       \
    __shared__ ushort As[2][128 * 64];                                         \
    __shared__ ushort Bs[2][256 * 64];                                         \
    const int tid = threadIdx.x;                                               \
    const int lane = tid & 63;                                                 \
    const int w = tid >> 6;                                                    \
    const int l15 = lane & 15;                                                 \
    const int quad = lane >> 4;                                                \
    const int wm = w >> 2, wn = w & 3;                                         \
    const int cx = l15 & 7;                                                    \
    const int lin = blockIdx.y * (NXT) + blockIdx.x;                           \
    const int wg = (lin & 7) * ((NWG) >> 3) + (lin >> 3);                      \
    const int rowBase = (wg / (NXT)) * 128;                                    \
    const int colBase = (wg % (NXT)) * 256;                                    \
    const int sr = tid >> 3, sc = tid & 7;                                     \
    const int ldst = sr * 64 + sc * 8;                                         \
    const ushort* aS0 = (Aptr) + (size_t)(rowBase + sr) * 1024 + ((sc ^ (sr & 7)) << 3); \
    const ushort* aS1 = aS0 + (size_t)64 * 1024;                               \
    const ushort* bS0 = (Btptr) + (size_t)(colBase + sr) * 1024 + ((sc ^ (sr & 7)) << 3); \
    const ushort* bS1 = bS0 + (size_t)64 * 1024;                               \
    const ushort* bS2 = bS0 + (size_t)128 * 1024;                              \
    const ushort* bS3 = bS0 + (size_t)192 * 1024;                              \
    f32x4 acc[4][4];                                                           \
    _Pragma("unroll")                                                          \
    for (int i_ = 0; i_ < 4; ++i_)                                             \
        _Pragma("unroll")                                                      \
        for (int j_ = 0; j_ < 4; ++j_) acc[i_][j_] = (f32x4){0.f, 0.f, 0.f, 0.f}; \
    STG_A(0) STG_B1(0) STG_B2(0) STG_B1(1) STG_B2(1)                           \
    asm volatile("s_waitcnt vmcnt(4)" ::: "memory");                           \
    __builtin_amdgcn_s_barrier();                                              \
    asm volatile("" ::: "memory");                                             \
    _Pragma("unroll 1")                                                        \
    for (int u = 0; u < 16; ++u) {                                             \
        const ushort* aRd = &As[u & 1][(wm * 64 + l15) * 64];                  \
        const ushort* bRd = &Bs[u & 1][(wn * 64 + l15) * 64];                  \
        const int c0 = (quad ^ cx) << 3, c1 = ((4 | quad) ^ cx) << 3;          \
        bf16x8 bF0[4], bF1[4];                                                 \
        _Pragma("unroll")                                                      \
        for (int ni = 0; ni < 4; ++ni) {                                       \
            bF0[ni] = *(const bf16x8*)(bRd + ni * 1024 + c0);                  \
            bF1[ni] = *(const bf16x8*)(bRd + ni * 1024 + c1);                  \
        }                                                                      \
        bf16x8 a00 = *(const bf16x8*)(aRd + c0);                               \
        bf16x8 a01 = *(const bf16x8*)(aRd + c1);                               \
        bf16x8 a10 = *(const bf16x8*)(aRd + 1024 + c0);                        \
        bf16x8 a11 = *(const bf16x8*)(aRd + 1024 + c1);                        \
        if (u + 1 < 16) { STG_A(u + 1) }                                       \
        __builtin_amdgcn_s_barrier();                                          \
        asm volatile("s_waitcnt lgkmcnt(0)" ::: "memory");                     \
        __builtin_amdgcn_sched_barrier(0);                                     \
        __builtin_amdgcn_s_setprio(1);                                         \
        _Pragma("unroll")                                                      \
        for (int ni = 0; ni < 4; ++ni) {                                       \
            acc[0][ni] = MFMA_BF16(a00, bF0[ni], acc[0][ni]);                  \
            acc[0][ni] = MFMA_BF16(a01, bF1[ni], acc[0][ni]);                  \
        }                                                                      \
        _Pragma("unroll")                                                      \
        for (int ni = 0; ni < 4; ++ni) {                                       \
            acc[1][ni] = MFMA_BF16(a10, bF0[ni], acc[1][ni]);                  \
            acc[1][ni] = MFMA_BF16(a11, bF1[ni], acc[1][ni]);                  \
        }                                                                      \
        __builtin_amdgcn_s_setprio(0);                                         \
        __builtin_amdgcn_s_barrier();                                          \
        asm volatile("" ::: "memory");                                         \
        bf16x8 a20 = *(const bf16x8*)(aRd + 2 * 1024 + c0);                    \
        bf16x8 a21 = *(const bf16x8*)(aRd + 2 * 1024 + c1);                    \
        bf16x8 a30 = *(const bf16x8*)(aRd + 3 * 1024 + c0);                    \
        bf16x8 a31 = *(const bf16x8*)(aRd + 3 * 1024 + c1);                    \
        if (u + 2 < 16) { STG_B1(u + 2) STG_B2(u + 2) }                        \
        __builtin_amdgcn_s_barrier();                                          \
        asm volatile("s_waitcnt lgkmcnt(0)" ::: "memory");                     \
        __builtin_amdgcn_sched_barrier(0);                                     \
        __builtin_amdgcn_s_setprio(1);                                         \
        _Pragma("unroll")                                                      \
        for (int ni = 0; ni < 4; ++ni) {                                       \
            acc[2][ni] = MFMA_BF16(a20, bF0[ni], acc[2][ni]);                  \
            acc[2][ni] = MFMA_BF16(a21, bF1[ni], acc[2][ni]);                  \
        }                                                                      \
        _Pragma("unroll")                                                      \
        for (int ni = 0; ni < 4; ++ni) {                                       \
            acc[3][ni] = MFMA_BF16(a30, bF0[ni], acc[3][ni]);                  \
            acc[3][ni] = MFMA_BF16(a31, bF1[ni], acc[3][ni]);                  \
        }                                                                      \
        __builtin_amdgcn_s_setprio(0);                                         \
        if (u < 14) { asm volatile("s_waitcnt vmcnt(4)" ::: "memory"); }       \
        else        { asm volatile("s_waitcnt vmcnt(0)" ::: "memory"); }       \
        __builtin_amdgcn_s_barrier();                                          \
        asm volatile("" ::: "memory");                                         \
    }

// ---------------------------------------------------------------------------
// GEMM 1: xb x Wt[0:3072] -> Q (pre-scaled by 0.125*log2e), K in [bh][n][64];
//         V directly transposed into Vt [bh*64+d][2048]
// ---------------------------------------------------------------------------
__global__ __launch_bounds__(512, 2) void gemm_qkv(
    const ushort* __restrict__ A, const ushort* __restrict__ Bt,
    ushort* __restrict__ Qb, ushort* __restrict__ Kb, ushort* __restrict__ Vt)
{
    GEMM_PIPE(A, Bt, 12, 768)

    const int seg = colBase >> 10;          // 0=Q 1=K 2=V
    if (seg == 2) {
        #pragma unroll
        for (int mi = 0; mi < 4; ++mi) {
            #pragma unroll
            for (int ni = 0; ni < 4; ++ni) {
                const int c = (colBase + wn*64 + ni*16 + l15) & 1023;
                const int h = c >> 6, d = c & 63;
                const int m = rowBase + wm*64 + mi*16 + quad*4;
                const int b = m >> 11, nn = m & 2047;
                ushort4 v;
                v.x = f2bf(acc[mi][ni][0]); v.y = f2bf(acc[mi][ni][1]);
                v.z = f2bf(acc[mi][ni][2]); v.w = f2bf(acc[mi][ni][3]);
                *(ushort4*)(Vt + ((size_t)(b*16 + h)*64 + d)*2048 + nn) = v;
            }
        }
    } else {
        ushort* dst = seg ? Kb : Qb;
        // Q pre-scale: 1/sqrt(64) * log2(e)  (softmax runs in base-2 domain)
        const float sc2 = seg ? 1.0f : 0.18033688011112042f;
        #pragma unroll
        for (int mi = 0; mi < 4; ++mi) {
            #pragma unroll
            for (int ni = 0; ni < 4; ++ni) {
                const int c = (colBase + wn*64 + ni*16 + l15) & 1023;
                const int h = c >> 6, d = c & 63;
                #pragma unroll
                for (int r = 0; r < 4; ++r) {
                    const int m = rowBase + wm*64 + mi*16 + quad*4 + r;
                    const int b = m >> 11, nn = m & 2047;
                    dst[((((size_t)b*16 + h)*2048 + nn) << 6) + d] = f2bf(acc[mi][ni][r] * sc2);
                }
            }
        }
    }
}

// ---------------------------------------------------------------------------
// GEMM 2: Ob x Wt[3072:4096] + bo -> fp32 out
// ---------------------------------------------------------------------------
__global__ __launch_bounds__(512, 2) void gemm_out(
    const ushort* __restrict__ A, const ushort* __restrict__ Bt,
    const float* __restrict__ bo, float* __restrict__ out)
{
    GEMM_PIPE(A, Bt, 4, 256)

    #pragma unroll
    for (int mi = 0; mi < 4; ++mi) {
        #pragma unroll
        for (int ni = 0; ni < 4; ++ni) {
            const int n = colBase + wn*64 + ni*16 + l15;
            const float bb = bo[n];
            #pragma unroll
            for (int r = 0; r < 4; ++r) {
                const int m = rowBase + wm*64 + mi*16 + quad*4 + r;
                out[(size_t)m * 1024 + n] = acc[mi][ni][r] + bb;
            }
        }
    }
}

// ---------------------------------------------------------------------------
// Flash attention v5: unpaired q-tiles (grid 1024, qt-descending dispatch),
// double-buffered LDS K/V, S^T trick, skip-rescale on no-new-max.
// Block = 4 waves x 32 q-rows = one 128-row q-tile.
// ---------------------------------------------------------------------------
__device__ __forceinline__ bf16x8 lds_frag(const ushort* S, int row, int chunk) {
    return *(const bf16x8*)(S + row * 64 + ((chunk ^ (row & 7)) << 3));
}

__global__ __launch_bounds__(256, 2) void flash_mfma(
    const ushort* __restrict__ Qb,
    const ushort* __restrict__ Kb,
    const ushort* __restrict__ Vt,
    ushort* __restrict__ Ob)
{
    __shared__ ushort Ks[2][4096];
    __shared__ ushort Vs[2][4096];
    __shared__ ushort PsAll[4][32][72];

    const int tid = threadIdx.x;
    const int w = tid >> 6;
    const int lane = tid & 63;
    const int l15 = lane & 15;
    const int quad = lane >> 4;
    ushort (*Ps)[72] = PsAll[w];

    const int blk = blockIdx.x;
    const int bh = ((blk & 7) << 3) | ((blk >> 3) & 7);
    const int qt = 15 - (blk >> 6);
    const int nt = 2 * qt + 2;
    const int rb0 = (qt << 7) + w * 32;

    const int sr0 = tid >> 3, sr1 = sr0 + 32;
    const int cg0 = (tid & 7) ^ (sr0 & 7);
    const int cg1 = (tid & 7) ^ (sr1 & 7);
    const ushort* kgb = Kb + (size_t)bh * 131072;
    const ushort* vgb = Vt + (size_t)bh * 131072;

    bf16x8 qf[2][2];
    #pragma unroll
    for (int mi = 0; mi < 2; ++mi) {
        const ushort* qp = Qb + ((size_t)bh * 2048 + rb0 + mi*16 + l15) * 64 + quad * 8;
        qf[mi][0] = *(const bf16x8*)qp;
        qf[mi][1] = *(const bf16x8*)(qp + 32);
    }

    bf16x8 bones;
    #pragma unroll
    for (int j = 0; j < 8; ++j) bones[j] = (short)0x3F80;   // bf16 1.0

    float m_r[2];
    f32x4 o[2][4], lacc[2];
    #pragma unroll
    for (int mi = 0; mi < 2; ++mi) {
        m_r[mi] = -INFINITY;
        lacc[mi] = (f32x4){0.f, 0.f, 0.f, 0.f};
        #pragma unroll
        for (int nb = 0; nb < 4; ++nb) o[mi][nb] = (f32x4){0.f, 0.f, 0.f, 0.f};
    }

    GLD_LDS(kgb + sr0*64 + cg0*8, &Ks[0][tid*8]);
    GLD_LDS(kgb + sr1*64 + cg1*8, &Ks[0][tid*8 + 2048]);
    GLD_LDS(vgb + (size_t)sr0*2048 + cg0*8, &Vs[0][tid*8]);
    GLD_LDS(vgb + (size_t)sr1*2048 + cg1*8, &Vs[0][tid*8 + 2048]);

    for (int t = 0; t < nt; ++t) {
        __syncthreads();
        const int cur = t & 1;
        if (t + 1 < nt) {
            const int jn = t + 1;
            ushort* kd = &Ks[cur ^ 1][tid * 8];
            ushort* vd = &Vs[cur ^ 1][tid * 8];
            GLD_LDS(kgb + (size_t)jn*4096 + sr0*64 + cg0*8, kd);
            GLD_LDS(kgb + (size_t)jn*4096 + sr1*64 + cg1*8, kd + 2048);
            GLD_LDS(vgb + (size_t)sr0*2048 + jn*64 + cg0*8, vd);
            GLD_LDS(vgb + (size_t)sr1*2048 + jn*64 + cg1*8, vd + 2048);
        }
        const int j0 = t << 6;
        if (j0 > rb0 + 31) continue;

        const ushort* Ksb = Ks[cur];
        const ushort* Vsb = Vs[cur];

        f32x4 St[2][4];
        #pragma unroll
        for (int kb = 0; kb < 4; ++kb) {
            bf16x8 ka = lds_frag(Ksb, kb*16 + l15, quad);
            bf16x8 kc = lds_frag(Ksb, kb*16 + l15, quad + 4);
            #pragma unroll
            for (int mi = 0; mi < 2; ++mi) {
                f32x4 s = (f32x4){0.f, 0.f, 0.f, 0.f};
                s = MFMA_BF16(ka, qf[mi][0], s);
                s = MFMA_BF16(kc, qf[mi][1], s);
                St[mi][kb] = s;
            }
        }

        #pragma unroll
        for (int mi = 0; mi < 2; ++mi) {
            const int qrow = rb0 + mi*16 + l15;
            if (j0 + 63 > rb0 + mi*16) {
                #pragma unroll
                for (int kb = 0; kb < 4; ++kb) {
                    const int kbase = j0 + kb*16 + quad*4;
                    #pragma unroll
                    for (int r = 0; r < 4; ++r)
                        if (kbase + r > qrow) St[mi][kb][r] = -INFINITY;
                }
            }
            f32x4 mv = St[mi][0];
            #pragma unroll
            for (int kb = 1; kb < 4; ++kb)
                #pragma unroll
                for (int r = 0; r < 4; ++r) mv[r] = fmaxf(mv[r], St[mi][kb][r]);
            float mx = fmaxf(fmaxf(mv[0], mv[1]), fmaxf(mv[2], mv[3]));
            mx = fmaxf(mx, __shfl_xor(mx, 16));
            mx = fmaxf(mx, __shfl_xor(mx, 32));
            const float mold = m_r[mi];
            const float mnew = fmaxf(mold, mx);
            if (__any(mnew > mold)) {
                m_r[mi] = mnew;
                const float corr = __builtin_amdgcn_exp2f(mold - mnew);
                float ct[4];
                #pragma unroll
                for (int r = 0; r < 4; ++r) ct[r] = __shfl(corr, quad*4 + r);
                #pragma unroll
                for (int r = 0; r < 4; ++r) lacc[mi][r] *= ct[r];
                #pragma unroll
                for (int nb = 0; nb < 4; ++nb)
                    #pragma unroll
                    for (int r = 0; r < 4; ++r) o[mi][nb][r] *= ct[r];
            }
            #pragma unroll
            for (int kb = 0; kb < 4; ++kb)
                #pragma unroll
                for (int r = 0; r < 4; ++r)
                    St[mi][kb][r] = __builtin_amdgcn_exp2f(St[mi][kb][r] - mnew);
            #pragma unroll
            for (int kb = 0; kb < 4; ++kb) {
                union { float f; unsigned u; } c0_, c1_, c2_, c3_;
                c0_.f = St[mi][kb][0]; c1_.f = St[mi][kb][1];
                c2_.f = St[mi][kb][2]; c3_.f = St[mi][kb][3];
                uint2 pk;
                pk.x = (c0_.u >> 16) | (c1_.u & 0xFFFF0000u);
                pk.y = (c2_.u >> 16) | (c3_.u & 0xFFFF0000u);
                *(uint2*)&Ps[mi*16 + l15][kb*16 + quad*4] = pk;
            }
        }

        bf16x8 pf[2][2];
        #pragma unroll
        for (int mi = 0; mi < 2; ++mi) {
            pf[mi][0] = *(const bf16x8*)&Ps[mi*16 + l15][quad * 8];
            pf[mi][1] = *(const bf16x8*)&Ps[mi*16 + l15][32 + quad * 8];
        }
        #pragma unroll
        for (int mi = 0; mi < 2; ++mi) {
            lacc[mi] = MFMA_BF16(pf[mi][0], bones, lacc[mi]);
            lacc[mi] = MFMA_BF16(pf[mi][1], bones, lacc[mi]);
        }
        #pragma unroll
        for (int nb = 0; nb < 4; ++nb) {
            bf16x8 va = lds_frag(Vsb, nb*16 + l15, quad);
            bf16x8 vc = lds_frag(Vsb, nb*16 + l15, quad + 4);
            #pragma unroll
            for (int mi = 0; mi < 2; ++mi) {
                o[mi][nb] = MFMA_BF16(pf[mi][0], va, o[mi][nb]);
                o[mi][nb] = MFMA_BF16(pf[mi][1], vc, o[mi][nb]);
            }
        }
    }

    const int b = bh >> 4, h = bh & 15;
    #pragma unroll
    for (int mi = 0; mi < 2; ++mi)
        #pragma unroll
        for (int r = 0; r < 4; ++r) {
            const int ig = rb0 + mi*16 + quad*4 + r;
            const float inv = 1.f / lacc[mi][r];
            ushort* op = Ob + ((size_t)(b * 2048 + ig)) * 1024 + h * 64 + l15;
            #pragma unroll
            for (int nb = 0; nb < 4; ++nb)
                op[nb * 16] = f2bf(o[mi][nb][r] * inv);
        }
}

// ---------------------------------------------------------------------------
extern "C" void kernel_launch(void* const* d_in, const int* in_sizes, int n_in,
                              void* d_out, int out_size, void* d_ws, size_t ws_size,
                              hipStream_t stream) {
    const float* x   = (const float*)d_in[0];
    const float* Wq  = (const float*)d_in[1];
    const float* Wkv = (const float*)d_in[2];
    const float* Wo  = (const float*)d_in[3];
    const float* bo  = (const float*)d_in[4];
    float* out = (float*)d_out;

    const size_t SEG = (size_t)8388608 * 2;   // 16 MB per bf16 [8192x1024]
    char* ws = (char*)d_ws;
    ushort* xb = (ushort*)(ws);
    ushort* Qb = (ushort*)(ws + SEG);
    ushort* Kb = (ushort*)(ws + SEG * 2);
    ushort* Vt = (ushort*)(ws + SEG * 3);     // [bh*64+d][2048]
    ushort* Ob = (ushort*)(ws + SEG * 4);
    ushort* Wt = (ushort*)(ws + SEG * 5);     // [4096][1024] bf16

    prep_all<<<dim3(4352), 256, 0, stream>>>(x, xb, Wq, Wkv, Wo, Wt);
    gemm_qkv<<<dim3(12, 64), 512, 0, stream>>>(xb, Wt, Qb, Kb, Vt);
    flash_mfma<<<dim3(1024), 256, 0, stream>>>(Qb, Kb, Vt, Ob);
    gemm_out<<<dim3(4, 64), 512, 0, stream>>>(Ob, Wt + (size_t)3072 * 1024, bo, out);
}